// Round 3
// baseline (19860.846 us; speedup 1.0000x reference)
//
#include <hip/hip_runtime.h>
#include <hip/hip_bf16.h>

#define B_ 32
#define S_ 512
#define IN_ 300
#define H_ 180
#define G4_ 720
#define OUT_ 60
#define R_ 16384   // B_*S_

// Unified fp32 weight-region sub-offsets (floats from wf base):
//   [linw 10800][linb 60][wih0 216000][wihr 388800][whh 518400][bias 2880]
#define WFO_LINW 0u
#define WFO_LINB 10800u
#define WFO_WIH0 10860u
#define WFO_WIHR 226860u
#define WFO_WHH  615660u
#define WFO_BIAS 1134060u
#define WF_TOT   1136940u

__device__ __forceinline__ float sigf(float x)   { return 1.f / (1.f + __expf(-x)); }
__device__ __forceinline__ float tanhf2(float x) { return 2.f / (1.f + __expf(-2.f * x)) - 1.f; }
__device__ __forceinline__ float toF(__hip_bfloat16 x) { return __bfloat162float(x); }
// flag: 0 => raw inputs are bf16, 1 => raw inputs are fp32
__device__ __forceinline__ float ldr(const void* p, long i, int fl) {
  return fl ? ((const float*)p)[i] : toF(((const __hip_bfloat16*)p)[i]);
}

// ---------------------------------------------------------------------------
// detect: decide whether raw inputs are bf16 or fp32 by exponent statistics
// of x's first 2048 uint16 words. fp32 low-halves are uniform bits -> many
// extreme bf16 exponents; genuine bf16 N(0,1) has none.
// ---------------------------------------------------------------------------
__global__ __launch_bounds__(256) void detect_kernel(
    const unsigned short* __restrict__ xw, int* __restrict__ flag) {
  __shared__ int cnt;
  if (threadIdx.x == 0) cnt = 0;
  __syncthreads();
  int lc = 0;
  for (int i = threadIdx.x; i < 2048; i += 256) {
    const int e = (xw[i] >> 7) & 0xFF;
    if (e >= 0xC0 || (e > 0 && e < 0x40)) lc++;
  }
  atomicAdd(&cnt, lc);
  __syncthreads();
  if (threadIdx.x == 0) *flag = (cnt > 100) ? 1 : 0;
}

// ---------------------------------------------------------------------------
// prep: raw weights -> fp32 ws region (unified ordering); bias = bih+bhh
// ---------------------------------------------------------------------------
__global__ __launch_bounds__(256) void prep_kernel(
    const void* __restrict__ wih0, const void* __restrict__ wihr,
    const void* __restrict__ whh,  const void* __restrict__ bih,
    const void* __restrict__ bhh,  const void* __restrict__ linw,
    const void* __restrict__ linb, float* __restrict__ wf,
    const int* __restrict__ flag) {
  const unsigned i = blockIdx.x * 256u + threadIdx.x;
  if (i >= WF_TOT) return;
  const int fl = *flag;
  float v;
  if (i < WFO_LINB)            v = ldr(linw, i, fl);
  else if (i < WFO_WIH0)       v = ldr(linb, i - WFO_LINB, fl);
  else if (i < WFO_WIHR)       v = ldr(wih0, i - WFO_WIH0, fl);
  else if (i < WFO_WHH)        v = ldr(wihr, i - WFO_WIHR, fl);
  else if (i < WFO_BIAS)       v = ldr(whh,  i - WFO_WHH, fl);
  else { unsigned j = i - WFO_BIAS; v = ldr(bih, j, fl) + ldr(bhh, j, fl); }
  wf[i] = v;
}

// ---------------------------------------------------------------------------
// gemm_xg: chunk input projection. Chunk rows rho = b*TC + tl.
//   out[rho][o] = sum_k A[b][t0+tl][k] * W[o*K+k] + bias[o]
//   a_kind: 0 = raw d_in (flag-dep dtype), 1 = ws fp32, 2 = ws bf16
// ---------------------------------------------------------------------------
__global__ __launch_bounds__(256) void gemm_xg(
    const void* __restrict__ a, int a_kind, const int* __restrict__ flag,
    const float* __restrict__ W, const float* __restrict__ bias,
    float* __restrict__ out, int K, int t0, int tcbits) {
  __shared__ __align__(16) float Ast[20][68];
  __shared__ __align__(16) float Bst[20][68];
  const int fl = *flag;
  const int tid = threadIdx.x;
  const int rho0 = blockIdx.x * 64;
  const int o0 = blockIdx.y * 64;
  const int tx = tid & 15, ty = tid >> 4;
  const int tcm = (1 << tcbits) - 1;
  float acc[4][4] = {};
  for (int k0 = 0; k0 < K; k0 += 20) {
    for (int e = tid; e < 1280; e += 256) {
      const int rl = e / 20, kk = e % 20;
      const int rho = rho0 + rl;
      const int bb = rho >> tcbits, tl = rho & tcm;
      const long gi = ((long)bb * S_ + t0 + tl) * K + k0 + kk;
      float av;
      if (a_kind == 1)      av = ((const float*)a)[gi];
      else if (a_kind == 2) av = toF(((const __hip_bfloat16*)a)[gi]);
      else                  av = ldr(a, gi, fl);
      Ast[kk][rl] = av;
      const int o = o0 + rl;
      Bst[kk][rl] = (o < G4_) ? W[(long)o * K + k0 + kk] : 0.f;
    }
    __syncthreads();
#pragma unroll
    for (int kk = 0; kk < 20; ++kk) {
      const float4 a4 = *(const float4*)&Ast[kk][ty * 4];
      const float4 b4 = *(const float4*)&Bst[kk][tx * 4];
      const float av[4] = {a4.x, a4.y, a4.z, a4.w};
      const float bv[4] = {b4.x, b4.y, b4.z, b4.w};
#pragma unroll
      for (int i = 0; i < 4; ++i)
#pragma unroll
        for (int j = 0; j < 4; ++j) acc[i][j] += av[i] * bv[j];
    }
    __syncthreads();
  }
#pragma unroll
  for (int i = 0; i < 4; ++i) {
    const int rho = rho0 + ty * 4 + i;
#pragma unroll
    for (int j = 0; j < 4; ++j) {
      const int o = o0 + tx * 4 + j;
      if (o < G4_) out[(long)rho * G4_ + o] = acc[i][j] + bias[o];
    }
  }
}

// ---------------------------------------------------------------------------
// lstm_chunk: one block per batch element; TC sequential steps.
//   h_mode: 0 = hout fp32, 1 = hout bf16
// ---------------------------------------------------------------------------
__global__ __launch_bounds__(768) void lstm_chunk(
    const float* __restrict__ xg, const float* __restrict__ whh,
    void* __restrict__ hout, int h_mode,
    float* __restrict__ st_h, float* __restrict__ st_c, int t0, int TC) {
  __shared__ __align__(16) float hbuf[192];
  __shared__ __align__(16) float gbuf[G4_];
  const int b = blockIdx.x;
  const int o = threadIdx.x;
  float c = 0.f;
  if (o < H_) {
    if (t0 == 0) hbuf[o] = 0.f;
    else { hbuf[o] = st_h[b * H_ + o]; c = st_c[b * H_ + o]; }
  }
  const float* wrow = whh + (long)(o < G4_ ? o : 0) * H_;
  __syncthreads();
  for (int tl = 0; tl < TC; ++tl) {
    if (o < G4_) {
      float a0 = 0.f, a1 = 0.f, a2 = 0.f, a3 = 0.f;
#pragma unroll 9
      for (int k4 = 0; k4 < 45; ++k4) {
        const float4 w = *(const float4*)(wrow + k4 * 4);
        const float4 h = *(const float4*)(hbuf + k4 * 4);
        a0 += w.x * h.x; a1 += w.y * h.y; a2 += w.z * h.z; a3 += w.w * h.w;
      }
      const float acc = xg[((long)b * TC + tl) * G4_ + o] + ((a0 + a1) + (a2 + a3));
      const bool isg = (o >= 2 * H_) && (o < 3 * H_);
      gbuf[o] = isg ? tanhf2(acc) : sigf(acc);
    }
    __syncthreads();
    if (o < H_) {
      c = gbuf[H_ + o] * c + gbuf[o] * gbuf[2 * H_ + o];
      const float h = gbuf[3 * H_ + o] * tanhf2(c);
      hbuf[o] = h;
      const long gi = ((long)b * S_ + t0 + tl) * H_ + o;
      if (h_mode == 0) ((float*)hout)[gi] = h;
      else ((__hip_bfloat16*)hout)[gi] = __float2bfloat16(h);
    }
    __syncthreads();
  }
  if (o < H_) { st_h[b * H_ + o] = hbuf[o]; st_c[b * H_ + o] = c; }
}

// ---------------------------------------------------------------------------
// linear: lin[b][c][s] = h[(b,s)] . linW[c] + linb[c]
// ---------------------------------------------------------------------------
__global__ __launch_bounds__(256) void linear_kernel(
    const void* __restrict__ h, int h_mode, const float* __restrict__ linw,
    const float* __restrict__ linb, float* __restrict__ out) {
  const int idx = blockIdx.x;
  const int s = (idx & 1) * 256 + threadIdx.x;
  const int c = (idx >> 1) % OUT_;
  const int b = idx / (2 * OUT_);
  const long hbase = ((long)b * S_ + s) * H_;
  const float* wr = linw + (long)c * H_;
  float acc = 0.f;
  if (h_mode == 0) {
    const float* hr = (const float*)h + hbase;
    float a0 = 0.f, a1 = 0.f, a2 = 0.f, a3 = 0.f;
#pragma unroll 9
    for (int k4 = 0; k4 < 45; ++k4) {
      const float4 hv = *(const float4*)(hr + k4 * 4);
      const float4 wv = *(const float4*)(wr + k4 * 4);
      a0 += hv.x * wv.x; a1 += hv.y * wv.y; a2 += hv.z * wv.z; a3 += hv.w * wv.w;
    }
    acc = ((a0 + a1) + (a2 + a3));
  } else {
    const __hip_bfloat16* hr = (const __hip_bfloat16*)h + hbase;
#pragma unroll 4
    for (int k = 0; k < H_; ++k) acc += toF(hr[k]) * wr[k];
  }
  out[((long)b * OUT_ + c) * S_ + s] = linb[c] + acc;
}

// ---------------------------------------------------------------------------
// mel block: out[b][c][s] = in[b][c][s] + bias + sum_{q,k} w*in[b][3i+q+j-1][s+k-2]
// ---------------------------------------------------------------------------
__global__ __launch_bounds__(256) void mel_kernel(
    const float* __restrict__ in, float* __restrict__ out,
    const void* __restrict__ mw, const void* __restrict__ mb,
    int l, const int* __restrict__ flag) {
  const int fl = *flag;
  const int idx = blockIdx.x;
  const int s = (idx & 1) * 256 + threadIdx.x;
  const int c = (idx >> 1) % OUT_;
  const int b = idx / (2 * OUT_);
  const int j = c % 3, i = c / 3;
  float acc = ldr(mb, (l * 3 + j) * 20 + i, fl);
  const long wbase = (long)((l * 3 + j) * 20 + i) * 15;
#pragma unroll
  for (int q = 0; q < 3; ++q) {
    const int ch = 3 * i + q + j - 1;
    if (ch < 0 || ch >= OUT_) continue;
    const float* xr = in + ((long)b * OUT_ + ch) * S_;
#pragma unroll
    for (int k = 0; k < 5; ++k) {
      const int sp = s + k - 2;
      if (sp < 0 || sp >= S_) continue;
      acc += ldr(mw, wbase + q * 5 + k, fl) * xr[sp];
    }
  }
  out[((long)b * OUT_ + c) * S_ + s] = acc + in[((long)b * OUT_ + c) * S_ + s];
}

// ---------------------------------------------------------------------------
// residual grouped conv + final transpose to [B][S][60]; store type per flag
// ---------------------------------------------------------------------------
__global__ __launch_bounds__(256) void res_kernel(
    const float* __restrict__ lin, const float* __restrict__ mel,
    const void* __restrict__ rw, const void* __restrict__ rb,
    void* __restrict__ outp, const int* __restrict__ flag) {
  const int fl = *flag;
  const int q = threadIdx.x >> 6, lane = threadIdx.x & 63;
  const int bs = blockIdx.x * 4 + q;
  const int b = bs / S_, s = bs % S_;
  if (lane >= OUT_) return;
  const int c = lane;
  float acc = ldr(rb, c, fl);
  const float* x0 = lin + ((long)b * OUT_ + c) * S_;
  const float* x1 = mel + ((long)b * OUT_ + c) * S_;
#pragma unroll
  for (int k = 0; k < 5; ++k) {
    const int sp = s + k - 2;
    if (sp < 0 || sp >= S_) continue;
    acc += ldr(rw, c * 10 + k, fl) * x0[sp] + ldr(rw, c * 10 + 5 + k, fl) * x1[sp];
  }
  const long oi = (long)bs * OUT_ + c;
  if (fl == 0) ((__hip_bfloat16*)outp)[oi] = __float2bfloat16(acc);
  else ((float*)outp)[oi] = acc;
}

// ---------------------------------------------------------------------------
extern "C" void kernel_launch(void* const* d_in, const int* in_sizes, int n_in,
                              void* d_out, int out_size, void* d_ws, size_t ws_size,
                              hipStream_t stream) {
  const void* x    = d_in[0];
  const void* wih0 = d_in[1];
  const void* wihr = d_in[2];
  const void* whh  = d_in[3];
  const void* bih  = d_in[4];
  const void* bhh  = d_in[5];
  const void* linw = d_in[6];
  const void* linb = d_in[7];
  const void* melw = d_in[8];
  const void* melb = d_in[9];
  const void* resw = d_in[10];
  const void* resb = d_in[11];

  float* ws = (float*)d_ws;
  const bool big = ws_size >= 40000000ull;  // Mode A needs 39,983,284 B

  // ---- layout (float offsets) ----
  unsigned FLAG_O, WF_O, XG_O, H0_O, H1_O, STH_O, STC_O, LIN_O, M1_O, M2_O;
  int TC, tcbits, h_mode;
  if (big) {  // Mode A: TC=128, h fp32. total 9,995,821 fl = 39.98 MB
    TC = 128; tcbits = 7; h_mode = 0;
    XG_O = 0u;            // [4096][720] = 2,949,120 ; epilogue aliases this
    H0_O = 2949120u;      // [16384][180] fp32
    H1_O = 5898240u;
    WF_O = 8847360u;      // 1,136,940
    STH_O = 9984300u; STC_O = 9990060u; FLAG_O = 9995820u;
    LIN_O = 0u; M1_O = 983040u; M2_O = 1966080u;
  } else {    // Mode C: TC=32, h bf16. total 4,834,876 fl = 19.34 MB
    TC = 32; tcbits = 5; h_mode = 1;
    FLAG_O = 0u;
    WF_O = 16u;           // ends 1,136,956
    XG_O = 1136956u;      // [1024][720] = 737,280 -> ends 1,874,236
    H0_O = 1874236u;      // bf16 [16384][180] = 1,474,560 fl -> 3,348,796
    H1_O = 3348796u;      // bf16 -> 4,823,356
    STH_O = 4823356u; STC_O = 4829116u;
    // epilogue span: [WF_O+10,876 .. 3,348,796) = 3,337,920 fl (wf-rest+xg+h0 dead)
    LIN_O = 10876u; M1_O = 993916u; M2_O = 1976956u;
  }
  int* flag = (int*)(ws + FLAG_O);
  float* wf  = ws + WF_O;
  float* xgc = ws + XG_O;
  float* sth = ws + STH_O;
  float* stc = ws + STC_O;
  float* lin = ws + LIN_O;
  float* m1  = ws + M1_O;
  float* m2  = ws + M2_O;
  void* hbufs[2] = {(void*)(ws + H0_O), (void*)(ws + H1_O)};

  // 1) dtype detect + weight prep
  detect_kernel<<<1, 256, 0, stream>>>((const unsigned short*)x, flag);
  prep_kernel<<<(WF_TOT + 255) / 256, 256, 0, stream>>>(
      wih0, wihr, whh, bih, bhh, linw, linb, wf, flag);

  // 2) 4 LSTM layers, each as (gemm chunk -> recurrence chunk) pairs
  const int NCH = S_ / TC;
  const dim3 ggrid(B_ * TC / 64, 12);
  const void* aprev = nullptr;  // previous layer h (ws)
  for (int l = 0; l < 4; ++l) {
    const float* whh_l  = wf + WFO_WHH + (unsigned)l * G4_ * H_;
    const float* bias_l = wf + WFO_BIAS + (unsigned)l * G4_;
    const float* wih_l  = (l == 0) ? (wf + WFO_WIH0)
                                   : (wf + WFO_WIHR + (unsigned)(l - 1) * G4_ * H_);
    const void* a  = (l == 0) ? x : aprev;
    const int a_kind = (l == 0) ? 0 : (h_mode == 0 ? 1 : 2);
    const int K = (l == 0) ? IN_ : H_;
    void* hcur = hbufs[l & 1];  // L0->h0, L1->h1, L2->h0, L3->h1 (final in h1)
    for (int ch = 0; ch < NCH; ++ch) {
      const int t0 = ch * TC;
      gemm_xg<<<ggrid, 256, 0, stream>>>(a, a_kind, flag, wih_l, bias_l, xgc, K, t0, tcbits);
      lstm_chunk<<<B_, 768, 0, stream>>>(xgc, whh_l, hcur, h_mode, sth, stc, t0, TC);
    }
    aprev = hcur;
  }

  // 3) linear -> [B][60][S]
  linear_kernel<<<B_ * OUT_ * 2, 256, 0, stream>>>(
      aprev, h_mode, wf + WFO_LINW, wf + WFO_LINB, lin);

  // 4) 3 mel smoothing blocks
  mel_kernel<<<B_ * OUT_ * 2, 256, 0, stream>>>(lin, m1, melw, melb, 0, flag);
  mel_kernel<<<B_ * OUT_ * 2, 256, 0, stream>>>(m1, m2, melw, melb, 1, flag);
  mel_kernel<<<B_ * OUT_ * 2, 256, 0, stream>>>(m2, m1, melw, melb, 2, flag);

  // 5) residual grouped conv + transpose; output dtype per flag
  res_kernel<<<R_ / 4, 256, 0, stream>>>(lin, m1, resw, resb, d_out, flag);
}

// Round 4
// 13547.652 us; speedup vs baseline: 1.4660x; 1.4660x over previous
//
#include <hip/hip_runtime.h>
#include <hip/hip_bf16.h>

#define B_ 32
#define S_ 512
#define IN_ 300
#define H_ 180
#define G4_ 720
#define OUT_ 60
#define R_ 16384   // B_*S_
#define NREG_ 128  // Whh k-slice held in VGPRs per thread

// Unified fp32 weight-region sub-offsets (floats from wf base):
//   [linw 10800][linb 60][wih0 216000][wihr 388800][whhT 518400][bias 2880]
//   whhT is TRANSPOSED per layer: [l][k][o], k in [0,180), o in [0,720)
#define WFO_LINW 0u
#define WFO_LINB 10800u
#define WFO_WIH0 10860u
#define WFO_WIHR 226860u
#define WFO_WHH  615660u
#define WFO_BIAS 1134060u
#define WF_TOT   1136940u

__device__ __forceinline__ float sigf(float x)   { return 1.f / (1.f + __expf(-x)); }
__device__ __forceinline__ float tanhf2(float x) { return 2.f / (1.f + __expf(-2.f * x)) - 1.f; }
__device__ __forceinline__ float toF(__hip_bfloat16 x) { return __bfloat162float(x); }
// flag: 0 => raw inputs are bf16, 1 => raw inputs are fp32
__device__ __forceinline__ float ldr(const void* p, long i, int fl) {
  return fl ? ((const float*)p)[i] : toF(((const __hip_bfloat16*)p)[i]);
}

// ---------------------------------------------------------------------------
// detect: bf16 vs fp32 raw inputs by exponent statistics of x's first 2048
// uint16 words (fp32 low-halves = uniform bits -> many extreme exponents).
// ---------------------------------------------------------------------------
__global__ __launch_bounds__(256) void detect_kernel(
    const unsigned short* __restrict__ xw, int* __restrict__ flag) {
  __shared__ int cnt;
  if (threadIdx.x == 0) cnt = 0;
  __syncthreads();
  int lc = 0;
  for (int i = threadIdx.x; i < 2048; i += 256) {
    const int e = (xw[i] >> 7) & 0xFF;
    if (e >= 0xC0 || (e > 0 && e < 0x40)) lc++;
  }
  atomicAdd(&cnt, lc);
  __syncthreads();
  if (threadIdx.x == 0) *flag = (cnt > 100) ? 1 : 0;
}

// ---------------------------------------------------------------------------
// prep: raw weights -> fp32 ws region; whh gets TRANSPOSED to [l][k][o];
// bias = bih+bhh
// ---------------------------------------------------------------------------
__global__ __launch_bounds__(256) void prep_kernel(
    const void* __restrict__ wih0, const void* __restrict__ wihr,
    const void* __restrict__ whh,  const void* __restrict__ bih,
    const void* __restrict__ bhh,  const void* __restrict__ linw,
    const void* __restrict__ linb, float* __restrict__ wf,
    const int* __restrict__ flag) {
  const unsigned i = blockIdx.x * 256u + threadIdx.x;
  if (i >= WF_TOT) return;
  const int fl = *flag;
  float v;
  if (i < WFO_LINB)            v = ldr(linw, i, fl);
  else if (i < WFO_WIH0)       v = ldr(linb, i - WFO_LINB, fl);
  else if (i < WFO_WIHR)       v = ldr(wih0, i - WFO_WIH0, fl);
  else if (i < WFO_WHH)        v = ldr(wihr, i - WFO_WIHR, fl);
  else if (i < WFO_BIAS) {
    const unsigned j = i - WFO_WHH;
    const unsigned l = j / 129600u, r = j - l * 129600u;
    const unsigned k = r / 720u, o = r - k * 720u;   // dst [l][k][o]
    v = ldr(whh, (long)l * 129600 + (long)o * 180 + k, fl);
  } else {
    const unsigned j = i - WFO_BIAS;
    v = ldr(bih, j, fl) + ldr(bhh, j, fl);
  }
  wf[i] = v;
}

// ---------------------------------------------------------------------------
// gemm_xg: chunk input projection. Chunk rows rho = b*TC + tl.
//   out[rho][o] = sum_k A[b][t0+tl][k] * W[o*K+k] + bias[o]
//   a_kind: 0 = raw d_in (flag-dep dtype), 1 = ws fp32, 2 = ws bf16
// ---------------------------------------------------------------------------
__global__ __launch_bounds__(256) void gemm_xg(
    const void* __restrict__ a, int a_kind, const int* __restrict__ flag,
    const float* __restrict__ W, const float* __restrict__ bias,
    float* __restrict__ out, int K, int t0, int tcbits) {
  __shared__ __align__(16) float Ast[20][68];
  __shared__ __align__(16) float Bst[20][68];
  const int fl = *flag;
  const int tid = threadIdx.x;
  const int rho0 = blockIdx.x * 64;
  const int o0 = blockIdx.y * 64;
  const int tx = tid & 15, ty = tid >> 4;
  const int tcm = (1 << tcbits) - 1;
  float acc[4][4] = {};
  for (int k0 = 0; k0 < K; k0 += 20) {
    for (int e = tid; e < 1280; e += 256) {
      const int rl = e / 20, kk = e % 20;
      const int rho = rho0 + rl;
      const int bb = rho >> tcbits, tl = rho & tcm;
      const long gi = ((long)bb * S_ + t0 + tl) * K + k0 + kk;
      float av;
      if (a_kind == 1)      av = ((const float*)a)[gi];
      else if (a_kind == 2) av = toF(((const __hip_bfloat16*)a)[gi]);
      else                  av = ldr(a, gi, fl);
      Ast[kk][rl] = av;
      const int o = o0 + rl;
      Bst[kk][rl] = (o < G4_) ? W[(long)o * K + k0 + kk] : 0.f;
    }
    __syncthreads();
#pragma unroll
    for (int kk = 0; kk < 20; ++kk) {
      const float4 a4 = *(const float4*)&Ast[kk][ty * 4];
      const float4 b4 = *(const float4*)&Bst[kk][tx * 4];
      const float av[4] = {a4.x, a4.y, a4.z, a4.w};
      const float bv[4] = {b4.x, b4.y, b4.z, b4.w};
#pragma unroll
      for (int i = 0; i < 4; ++i)
#pragma unroll
        for (int j = 0; j < 4; ++j) acc[i][j] += av[i] * bv[j];
    }
    __syncthreads();
  }
#pragma unroll
  for (int i = 0; i < 4; ++i) {
    const int rho = rho0 + ty * 4 + i;
#pragma unroll
    for (int j = 0; j < 4; ++j) {
      const int o = o0 + tx * 4 + j;
      if (o < G4_) out[(long)rho * G4_ + o] = acc[i][j] + bias[o];
    }
  }
}

// ---------------------------------------------------------------------------
// lstm_chunk: one block per batch element; TC sequential steps.
//   wt: [180][720] transposed layer slice. First NREG_ k's pinned in VGPRs
//   (loaded once, coalesced); tail 52 k's streamed coalesced from L2 each
//   step. zoff is always 0 — it launders the tail pointer so the compiler
//   cannot hoist the 52 loop-invariant loads into registers (VGPR budget).
//   h_mode: 0 = hout fp32, 1 = hout bf16
// ---------------------------------------------------------------------------
__global__ __launch_bounds__(768) void lstm_chunk(
    const float* __restrict__ xg, const float* __restrict__ wt,
    void* __restrict__ hout, int h_mode,
    float* __restrict__ st_h, float* __restrict__ st_c,
    int t0, int TC, int zoff) {
  __shared__ __align__(16) float hbuf[192];
  __shared__ float gbuf[G4_];
  const int b = blockIdx.x;
  const int o = threadIdx.x;
  const bool act = o < G4_;
  float w[NREG_];
  if (act) {
#pragma unroll
    for (int j = 0; j < NREG_; ++j) w[j] = wt[(long)j * G4_ + o];
  }
  float c = 0.f;
  if (o < H_) {
    if (t0 == 0) hbuf[o] = 0.f;
    else { hbuf[o] = st_h[b * H_ + o]; c = st_c[b * H_ + o]; }
  }
  const float* wtail0 = wt + (long)NREG_ * G4_ + o;
  const float* xgp = xg + (long)b * TC * G4_ + o;
  __syncthreads();
  for (int tl = 0; tl < TC; ++tl) {
    if (act) {
      float a0 = xgp[(long)tl * G4_], a1 = 0.f, a2 = 0.f, a3 = 0.f;
      const float* wp = wtail0 + (long)zoff * tl;  // zoff==0: same ptr, opaque
#pragma unroll
      for (int k4 = 0; k4 < NREG_ / 4; ++k4) {
        const float4 h4 = *(const float4*)&hbuf[k4 * 4];
        a0 += w[k4 * 4 + 0] * h4.x; a1 += w[k4 * 4 + 1] * h4.y;
        a2 += w[k4 * 4 + 2] * h4.z; a3 += w[k4 * 4 + 3] * h4.w;
      }
#pragma unroll
      for (int kb = 0; kb < (H_ - NREG_) / 4; ++kb) {
        const float4 h4 = *(const float4*)&hbuf[NREG_ + kb * 4];
        a0 += wp[(kb * 4 + 0) * G4_] * h4.x; a1 += wp[(kb * 4 + 1) * G4_] * h4.y;
        a2 += wp[(kb * 4 + 2) * G4_] * h4.z; a3 += wp[(kb * 4 + 3) * G4_] * h4.w;
      }
      const float acc = (a0 + a1) + (a2 + a3);
      const bool isg = (o >= 2 * H_) && (o < 3 * H_);
      gbuf[o] = isg ? tanhf2(acc) : sigf(acc);
    }
    __syncthreads();
    if (o < H_) {
      c = gbuf[H_ + o] * c + gbuf[o] * gbuf[2 * H_ + o];
      const float h = gbuf[3 * H_ + o] * tanhf2(c);
      hbuf[o] = h;
      const long gi = ((long)b * S_ + t0 + tl) * H_ + o;
      if (h_mode == 0) ((float*)hout)[gi] = h;
      else ((__hip_bfloat16*)hout)[gi] = __float2bfloat16(h);
    }
    __syncthreads();
  }
  if (o < H_) { st_h[b * H_ + o] = hbuf[o]; st_c[b * H_ + o] = c; }
}

// ---------------------------------------------------------------------------
// linear: lin[b][c][s] = h[(b,s)] . linW[c] + linb[c]
// ---------------------------------------------------------------------------
__global__ __launch_bounds__(256) void linear_kernel(
    const void* __restrict__ h, int h_mode, const float* __restrict__ linw,
    const float* __restrict__ linb, float* __restrict__ out) {
  const int idx = blockIdx.x;
  const int s = (idx & 1) * 256 + threadIdx.x;
  const int c = (idx >> 1) % OUT_;
  const int b = idx / (2 * OUT_);
  const long hbase = ((long)b * S_ + s) * H_;
  const float* wr = linw + (long)c * H_;
  float acc = 0.f;
  if (h_mode == 0) {
    const float* hr = (const float*)h + hbase;
    float a0 = 0.f, a1 = 0.f, a2 = 0.f, a3 = 0.f;
#pragma unroll 9
    for (int k4 = 0; k4 < 45; ++k4) {
      const float4 hv = *(const float4*)(hr + k4 * 4);
      const float4 wv = *(const float4*)(wr + k4 * 4);
      a0 += hv.x * wv.x; a1 += hv.y * wv.y; a2 += hv.z * wv.z; a3 += hv.w * wv.w;
    }
    acc = ((a0 + a1) + (a2 + a3));
  } else {
    const __hip_bfloat16* hr = (const __hip_bfloat16*)h + hbase;
#pragma unroll 4
    for (int k = 0; k < H_; ++k) acc += toF(hr[k]) * wr[k];
  }
  out[((long)b * OUT_ + c) * S_ + s] = linb[c] + acc;
}

// ---------------------------------------------------------------------------
// mel block: out[b][c][s] = in[b][c][s] + bias + sum_{q,k} w*in[b][3i+q+j-1][s+k-2]
// ---------------------------------------------------------------------------
__global__ __launch_bounds__(256) void mel_kernel(
    const float* __restrict__ in, float* __restrict__ out,
    const void* __restrict__ mw, const void* __restrict__ mb,
    int l, const int* __restrict__ flag) {
  const int fl = *flag;
  const int idx = blockIdx.x;
  const int s = (idx & 1) * 256 + threadIdx.x;
  const int c = (idx >> 1) % OUT_;
  const int b = idx / (2 * OUT_);
  const int j = c % 3, i = c / 3;
  float acc = ldr(mb, (l * 3 + j) * 20 + i, fl);
  const long wbase = (long)((l * 3 + j) * 20 + i) * 15;
#pragma unroll
  for (int q = 0; q < 3; ++q) {
    const int ch = 3 * i + q + j - 1;
    if (ch < 0 || ch >= OUT_) continue;
    const float* xr = in + ((long)b * OUT_ + ch) * S_;
#pragma unroll
    for (int k = 0; k < 5; ++k) {
      const int sp = s + k - 2;
      if (sp < 0 || sp >= S_) continue;
      acc += ldr(mw, wbase + q * 5 + k, fl) * xr[sp];
    }
  }
  out[((long)b * OUT_ + c) * S_ + s] = acc + in[((long)b * OUT_ + c) * S_ + s];
}

// ---------------------------------------------------------------------------
// residual grouped conv + final transpose to [B][S][60]; store type per flag
// ---------------------------------------------------------------------------
__global__ __launch_bounds__(256) void res_kernel(
    const float* __restrict__ lin, const float* __restrict__ mel,
    const void* __restrict__ rw, const void* __restrict__ rb,
    void* __restrict__ outp, const int* __restrict__ flag) {
  const int fl = *flag;
  const int q = threadIdx.x >> 6, lane = threadIdx.x & 63;
  const int bs = blockIdx.x * 4 + q;
  const int b = bs / S_, s = bs % S_;
  if (lane >= OUT_) return;
  const int c = lane;
  float acc = ldr(rb, c, fl);
  const float* x0 = lin + ((long)b * OUT_ + c) * S_;
  const float* x1 = mel + ((long)b * OUT_ + c) * S_;
#pragma unroll
  for (int k = 0; k < 5; ++k) {
    const int sp = s + k - 2;
    if (sp < 0 || sp >= S_) continue;
    acc += ldr(rw, c * 10 + k, fl) * x0[sp] + ldr(rw, c * 10 + 5 + k, fl) * x1[sp];
  }
  const long oi = (long)bs * OUT_ + c;
  if (fl == 0) ((__hip_bfloat16*)outp)[oi] = __float2bfloat16(acc);
  else ((float*)outp)[oi] = acc;
}

// ---------------------------------------------------------------------------
extern "C" void kernel_launch(void* const* d_in, const int* in_sizes, int n_in,
                              void* d_out, int out_size, void* d_ws, size_t ws_size,
                              hipStream_t stream) {
  const void* x    = d_in[0];
  const void* wih0 = d_in[1];
  const void* wihr = d_in[2];
  const void* whh  = d_in[3];
  const void* bih  = d_in[4];
  const void* bhh  = d_in[5];
  const void* linw = d_in[6];
  const void* linb = d_in[7];
  const void* melw = d_in[8];
  const void* melb = d_in[9];
  const void* resw = d_in[10];
  const void* resb = d_in[11];

  float* ws = (float*)d_ws;
  const bool big = ws_size >= 40000000ull;  // Mode A needs 39,983,284 B

  // ---- layout (float offsets) ----
  unsigned FLAG_O, WF_O, XG_O, H0_O, H1_O, STH_O, STC_O, LIN_O, M1_O, M2_O;
  int TC, tcbits, h_mode;
  if (big) {  // Mode A: TC=128, h fp32. total 9,995,821 fl = 39.98 MB
    TC = 128; tcbits = 7; h_mode = 0;
    XG_O = 0u;            // [4096][720] = 2,949,120 ; epilogue aliases this
    H0_O = 2949120u;      // [16384][180] fp32
    H1_O = 5898240u;
    WF_O = 8847360u;      // 1,136,940
    STH_O = 9984300u; STC_O = 9990060u; FLAG_O = 9995820u;
    LIN_O = 0u; M1_O = 983040u; M2_O = 1966080u;
  } else {    // Mode C: TC=32, h bf16. total 4,834,876 fl = 19.34 MB
    TC = 32; tcbits = 5; h_mode = 1;
    FLAG_O = 0u;
    WF_O = 16u;           // ends 1,136,956
    XG_O = 1136956u;      // [1024][720] = 737,280 -> ends 1,874,236
    H0_O = 1874236u;      // bf16 [16384][180] = 1,474,560 fl -> 3,348,796
    H1_O = 3348796u;      // bf16 -> 4,823,356
    STH_O = 4823356u; STC_O = 4829116u;
    LIN_O = 10876u; M1_O = 993916u; M2_O = 1976956u;
  }
  int* flag = (int*)(ws + FLAG_O);
  float* wf  = ws + WF_O;
  float* xgc = ws + XG_O;
  float* sth = ws + STH_O;
  float* stc = ws + STC_O;
  float* lin = ws + LIN_O;
  float* m1  = ws + M1_O;
  float* m2  = ws + M2_O;
  void* hbufs[2] = {(void*)(ws + H0_O), (void*)(ws + H1_O)};

  // 1) dtype detect + weight prep (whh transposed to [k][o])
  detect_kernel<<<1, 256, 0, stream>>>((const unsigned short*)x, flag);
  prep_kernel<<<(WF_TOT + 255) / 256, 256, 0, stream>>>(
      wih0, wihr, whh, bih, bhh, linw, linb, wf, flag);

  // 2) 4 LSTM layers, each as (gemm chunk -> recurrence chunk) pairs
  const int NCH = S_ / TC;
  const dim3 ggrid(B_ * TC / 64, 12);
  const void* aprev = nullptr;
  for (int l = 0; l < 4; ++l) {
    const float* wt_l   = wf + WFO_WHH + (unsigned)l * G4_ * H_;   // [180][720]
    const float* bias_l = wf + WFO_BIAS + (unsigned)l * G4_;
    const float* wih_l  = (l == 0) ? (wf + WFO_WIH0)
                                   : (wf + WFO_WIHR + (unsigned)(l - 1) * G4_ * H_);
    const void* a  = (l == 0) ? x : aprev;
    const int a_kind = (l == 0) ? 0 : (h_mode == 0 ? 1 : 2);
    const int K = (l == 0) ? IN_ : H_;
    void* hcur = hbufs[l & 1];
    for (int ch = 0; ch < NCH; ++ch) {
      const int t0 = ch * TC;
      gemm_xg<<<ggrid, 256, 0, stream>>>(a, a_kind, flag, wih_l, bias_l, xgc, K, t0, tcbits);
      lstm_chunk<<<B_, 768, 0, stream>>>(xgc, wt_l, hcur, h_mode, sth, stc, t0, TC, /*zoff=*/0);
    }
    aprev = hcur;
  }

  // 3) linear -> [B][60][S]
  linear_kernel<<<B_ * OUT_ * 2, 256, 0, stream>>>(
      aprev, h_mode, wf + WFO_LINW, wf + WFO_LINB, lin);

  // 4) 3 mel smoothing blocks
  mel_kernel<<<B_ * OUT_ * 2, 256, 0, stream>>>(lin, m1, melw, melb, 0, flag);
  mel_kernel<<<B_ * OUT_ * 2, 256, 0, stream>>>(m1, m2, melw, melb, 1, flag);
  mel_kernel<<<B_ * OUT_ * 2, 256, 0, stream>>>(m2, m1, melw, melb, 2, flag);

  // 5) residual grouped conv + transpose; output dtype per flag
  res_kernel<<<R_ / 4, 256, 0, stream>>>(lin, m1, resw, resb, d_out, flag);
}

// Round 5
// 4423.007 us; speedup vs baseline: 4.4903x; 3.0630x over previous
//
#include <hip/hip_runtime.h>
#include <hip/hip_bf16.h>

#define B_ 32
#define S_ 512
#define IN_ 300
#define H_ 180
#define G4_ 720
#define OUT_ 60
#define R_ 16384   // B_*S_
#define NPK_ 92    // f16-pair regs per thread (90 data + 2 zero pad)

// Unified fp32 weight-region sub-offsets (floats from wf base):
//   [linw 10800][linb 60][wih0 216000][wihr 388800][whh-region 518400][bias 2880]
//   whh-region holds PACKED f16-pair whh^T: [l][92][720] uints (264,960), rest 0.
#define WFO_LINW 0u
#define WFO_LINB 10800u
#define WFO_WIH0 10860u
#define WFO_WIHR 226860u
#define WFO_WHH  615660u
#define WFO_BIAS 1134060u
#define WF_TOT   1136940u
#define PKL_ (NPK_ * G4_)   // 66,240 uints per layer

#if defined(__has_builtin)
#if __has_builtin(__builtin_amdgcn_fdot2)
#define HAVE_FDOT2 1
#endif
#endif

typedef _Float16 f16x2 __attribute__((ext_vector_type(2)));

__device__ __forceinline__ float sigf(float x)   { return 1.f / (1.f + __expf(-x)); }
__device__ __forceinline__ float tanhf2(float x) { return 2.f / (1.f + __expf(-2.f * x)) - 1.f; }
__device__ __forceinline__ float toF(__hip_bfloat16 x) { return __bfloat162float(x); }
__device__ __forceinline__ float ldr(const void* p, long i, int fl) {
  return fl ? ((const float*)p)[i] : toF(((const __hip_bfloat16*)p)[i]);
}
__device__ __forceinline__ unsigned f16b(_Float16 h) {
  union { _Float16 f; unsigned short s; } x; x.f = h; return x.s;
}
__device__ __forceinline__ float h2f(unsigned s) {
  union { unsigned short s; _Float16 f; } x; x.s = (unsigned short)(s & 0xFFFFu);
  return (float)x.f;
}
__device__ __forceinline__ f16x2 u2h(unsigned u) {
  union { unsigned u; f16x2 v; } x; x.u = u; return x.v;
}

// ---------------------------------------------------------------------------
// detect: bf16 vs fp32 raw inputs via exponent stats of x's first 2048 words
// ---------------------------------------------------------------------------
__global__ __launch_bounds__(256) void detect_kernel(
    const unsigned short* __restrict__ xw, int* __restrict__ flag) {
  __shared__ int cnt;
  if (threadIdx.x == 0) cnt = 0;
  __syncthreads();
  int lc = 0;
  for (int i = threadIdx.x; i < 2048; i += 256) {
    const int e = (xw[i] >> 7) & 0xFF;
    if (e >= 0xC0 || (e > 0 && e < 0x40)) lc++;
  }
  atomicAdd(&cnt, lc);
  __syncthreads();
  if (threadIdx.x == 0) *flag = (cnt > 100) ? 1 : 0;
}

// ---------------------------------------------------------------------------
// prep: raw weights -> ws. whh packed as f16 pairs transposed [l][jp][o]
// (pair jp = k's 2jp,2jp+1; jp>=90 zero). Others fp32. bias = bih+bhh.
// ---------------------------------------------------------------------------
__global__ __launch_bounds__(256) void prep_kernel(
    const void* __restrict__ wih0, const void* __restrict__ wihr,
    const void* __restrict__ whh,  const void* __restrict__ bih,
    const void* __restrict__ bhh,  const void* __restrict__ linw,
    const void* __restrict__ linb, float* __restrict__ wf,
    const int* __restrict__ flag) {
  const unsigned i = blockIdx.x * 256u + threadIdx.x;
  if (i >= WF_TOT) return;
  const int fl = *flag;
  if (i >= WFO_WHH && i < WFO_BIAS) {
    const unsigned j = i - WFO_WHH;
    unsigned u = 0u;
    if (j < 4u * PKL_) {
      const unsigned l = j / PKL_, r = j - l * PKL_;
      const unsigned jp = r / G4_, o = r - jp * G4_;
      if (jp < 90u) {
        const long base = (long)l * 129600 + (long)o * H_;
        const _Float16 w0 = (_Float16)ldr(whh, base + 2 * jp, fl);
        const _Float16 w1 = (_Float16)ldr(whh, base + 2 * jp + 1, fl);
        u = f16b(w0) | (f16b(w1) << 16);
      }
    }
    ((unsigned*)wf)[i] = u;
    return;
  }
  float v;
  if (i < WFO_LINB)            v = ldr(linw, i, fl);
  else if (i < WFO_WIH0)       v = ldr(linb, i - WFO_LINB, fl);
  else if (i < WFO_WIHR)       v = ldr(wih0, i - WFO_WIH0, fl);
  else if (i < WFO_WHH)        v = ldr(wihr, i - WFO_WIHR, fl);
  else { const unsigned j = i - WFO_BIAS; v = ldr(bih, j, fl) + ldr(bhh, j, fl); }
  wf[i] = v;
}

// ---------------------------------------------------------------------------
// gemm_xg: chunk input projection (unchanged from R3)
// ---------------------------------------------------------------------------
__global__ __launch_bounds__(256) void gemm_xg(
    const void* __restrict__ a, int a_kind, const int* __restrict__ flag,
    const float* __restrict__ W, const float* __restrict__ bias,
    float* __restrict__ out, int K, int t0, int tcbits) {
  __shared__ __align__(16) float Ast[20][68];
  __shared__ __align__(16) float Bst[20][68];
  const int fl = *flag;
  const int tid = threadIdx.x;
  const int rho0 = blockIdx.x * 64;
  const int o0 = blockIdx.y * 64;
  const int tx = tid & 15, ty = tid >> 4;
  const int tcm = (1 << tcbits) - 1;
  float acc[4][4] = {};
  for (int k0 = 0; k0 < K; k0 += 20) {
    for (int e = tid; e < 1280; e += 256) {
      const int rl = e / 20, kk = e % 20;
      const int rho = rho0 + rl;
      const int bb = rho >> tcbits, tl = rho & tcm;
      const long gi = ((long)bb * S_ + t0 + tl) * K + k0 + kk;
      float av;
      if (a_kind == 1)      av = ((const float*)a)[gi];
      else if (a_kind == 2) av = toF(((const __hip_bfloat16*)a)[gi]);
      else                  av = ldr(a, gi, fl);
      Ast[kk][rl] = av;
      const int o = o0 + rl;
      Bst[kk][rl] = (o < G4_) ? W[(long)o * K + k0 + kk] : 0.f;
    }
    __syncthreads();
#pragma unroll
    for (int kk = 0; kk < 20; ++kk) {
      const float4 a4 = *(const float4*)&Ast[kk][ty * 4];
      const float4 b4 = *(const float4*)&Bst[kk][tx * 4];
      const float av[4] = {a4.x, a4.y, a4.z, a4.w};
      const float bv[4] = {b4.x, b4.y, b4.z, b4.w};
#pragma unroll
      for (int i = 0; i < 4; ++i)
#pragma unroll
        for (int j = 0; j < 4; ++j) acc[i][j] += av[i] * bv[j];
    }
    __syncthreads();
  }
#pragma unroll
  for (int i = 0; i < 4; ++i) {
    const int rho = rho0 + ty * 4 + i;
#pragma unroll
    for (int j = 0; j < 4; ++j) {
      const int o = o0 + tx * 4 + j;
      if (o < G4_) out[(long)rho * G4_ + o] = acc[i][j] + bias[o];
    }
  }
}

// ---------------------------------------------------------------------------
// lstm_chunk: one block per batch; TC sequential steps.
//   Whh fully register-resident as 92 packed f16 pairs per thread.
//   h split hi/lo f16 pairs in LDS (wave-uniform broadcast reads), dot via
//   V_DOT2_F32_F16. __launch_bounds__(768,3) -> VGPR cap ~168, no spill.
// ---------------------------------------------------------------------------
__global__ __launch_bounds__(768, 3) void lstm_chunk(
    const float* __restrict__ xg, const unsigned* __restrict__ wpk,
    void* __restrict__ hout, int h_mode,
    float* __restrict__ st_h, float* __restrict__ st_c, int t0, int TC) {
  __shared__ __align__(16) unsigned hpk_hi[NPK_];
  __shared__ __align__(16) unsigned hpk_lo[NPK_];
  __shared__ float gbuf[G4_];
  const int b = blockIdx.x;
  const int o = threadIdx.x;
  const bool act = o < G4_;
  unsigned w[NPK_];
  if (act) {
#pragma unroll
    for (int j = 0; j < NPK_; ++j) w[j] = wpk[j * G4_ + o];
  }
  float c = 0.f;
  if (o == 180 || o == 181) { hpk_hi[o - 90] = 0u; hpk_lo[o - 90] = 0u; }
  if (o < H_) {
    float h = 0.f;
    if (t0 != 0) { h = st_h[b * H_ + o]; c = st_c[b * H_ + o]; }
    const _Float16 hh = (_Float16)h;
    const _Float16 hl = (_Float16)(h - (float)hh);
    const unsigned v = f16b(hh) | (f16b(hl) << 16);
    const unsigned nx = __shfl_down(v, 1);
    if ((o & 1) == 0) {
      hpk_hi[o >> 1] = (v & 0xFFFFu) | ((nx & 0xFFFFu) << 16);
      hpk_lo[o >> 1] = (v >> 16) | (nx & 0xFFFF0000u);
    }
  }
  const float* xgp = xg + (long)b * TC * G4_ + o;
  float xcur = act ? xgp[0] : 0.f;
  __syncthreads();
  for (int tl = 0; tl < TC; ++tl) {
    if (act) {
      float a0 = xcur, a1 = 0.f, a2 = 0.f, a3 = 0.f;
#pragma unroll
      for (int j4 = 0; j4 < NPK_ / 4; ++j4) {
        const uint4 hh = *(const uint4*)&hpk_hi[j4 * 4];
        const uint4 hl = *(const uint4*)&hpk_lo[j4 * 4];
#ifdef HAVE_FDOT2
        a0 = __builtin_amdgcn_fdot2(u2h(hh.x), u2h(w[j4 * 4 + 0]), a0, false);
        a1 = __builtin_amdgcn_fdot2(u2h(hh.y), u2h(w[j4 * 4 + 1]), a1, false);
        a2 = __builtin_amdgcn_fdot2(u2h(hh.z), u2h(w[j4 * 4 + 2]), a2, false);
        a3 = __builtin_amdgcn_fdot2(u2h(hh.w), u2h(w[j4 * 4 + 3]), a3, false);
        a0 = __builtin_amdgcn_fdot2(u2h(hl.x), u2h(w[j4 * 4 + 0]), a0, false);
        a1 = __builtin_amdgcn_fdot2(u2h(hl.y), u2h(w[j4 * 4 + 1]), a1, false);
        a2 = __builtin_amdgcn_fdot2(u2h(hl.z), u2h(w[j4 * 4 + 2]), a2, false);
        a3 = __builtin_amdgcn_fdot2(u2h(hl.w), u2h(w[j4 * 4 + 3]), a3, false);
#else
        const unsigned w0 = w[j4 * 4 + 0], w1 = w[j4 * 4 + 1];
        const unsigned w2 = w[j4 * 4 + 2], w3 = w[j4 * 4 + 3];
        a0 += (h2f(hh.x) + h2f(hl.x)) * h2f(w0) +
              (h2f(hh.x >> 16) + h2f(hl.x >> 16)) * h2f(w0 >> 16);
        a1 += (h2f(hh.y) + h2f(hl.y)) * h2f(w1) +
              (h2f(hh.y >> 16) + h2f(hl.y >> 16)) * h2f(w1 >> 16);
        a2 += (h2f(hh.z) + h2f(hl.z)) * h2f(w2) +
              (h2f(hh.z >> 16) + h2f(hl.z >> 16)) * h2f(w2 >> 16);
        a3 += (h2f(hh.w) + h2f(hl.w)) * h2f(w3) +
              (h2f(hh.w >> 16) + h2f(hl.w >> 16)) * h2f(w3 >> 16);
#endif
      }
      const float acc = (a0 + a1) + (a2 + a3);
      const bool isg = (o >= 2 * H_) && (o < 3 * H_);
      gbuf[o] = isg ? tanhf2(acc) : sigf(acc);
      const int tn = (tl + 1 < TC) ? tl + 1 : tl;   // prefetch next xg
      xcur = xgp[(long)tn * G4_];
    }
    __syncthreads();
    if (o < H_) {
      c = gbuf[H_ + o] * c + gbuf[o] * gbuf[2 * H_ + o];
      const float h = gbuf[3 * H_ + o] * tanhf2(c);
      const long gi = ((long)b * S_ + t0 + tl) * H_ + o;
      if (h_mode == 0) ((float*)hout)[gi] = h;
      else ((__hip_bfloat16*)hout)[gi] = __float2bfloat16(h);
      const _Float16 hh2 = (_Float16)h;
      const _Float16 hl2 = (_Float16)(h - (float)hh2);
      const unsigned v = f16b(hh2) | (f16b(hl2) << 16);
      const unsigned nx = __shfl_down(v, 1);
      if ((o & 1) == 0) {
        hpk_hi[o >> 1] = (v & 0xFFFFu) | ((nx & 0xFFFFu) << 16);
        hpk_lo[o >> 1] = (v >> 16) | (nx & 0xFFFF0000u);
      }
      if (tl == TC - 1) { st_h[b * H_ + o] = h; st_c[b * H_ + o] = c; }
    }
    __syncthreads();
  }
}

// ---------------------------------------------------------------------------
// linear: lin[b][c][s] = h[(b,s)] . linW[c] + linb[c]
// ---------------------------------------------------------------------------
__global__ __launch_bounds__(256) void linear_kernel(
    const void* __restrict__ h, int h_mode, const float* __restrict__ linw,
    const float* __restrict__ linb, float* __restrict__ out) {
  const int idx = blockIdx.x;
  const int s = (idx & 1) * 256 + threadIdx.x;
  const int c = (idx >> 1) % OUT_;
  const int b = idx / (2 * OUT_);
  const long hbase = ((long)b * S_ + s) * H_;
  const float* wr = linw + (long)c * H_;
  float acc = 0.f;
  if (h_mode == 0) {
    const float* hr = (const float*)h + hbase;
    float a0 = 0.f, a1 = 0.f, a2 = 0.f, a3 = 0.f;
#pragma unroll 9
    for (int k4 = 0; k4 < 45; ++k4) {
      const float4 hv = *(const float4*)(hr + k4 * 4);
      const float4 wv = *(const float4*)(wr + k4 * 4);
      a0 += hv.x * wv.x; a1 += hv.y * wv.y; a2 += hv.z * wv.z; a3 += hv.w * wv.w;
    }
    acc = ((a0 + a1) + (a2 + a3));
  } else {
    const __hip_bfloat16* hr = (const __hip_bfloat16*)h + hbase;
#pragma unroll 4
    for (int k = 0; k < H_; ++k) acc += toF(hr[k]) * wr[k];
  }
  out[((long)b * OUT_ + c) * S_ + s] = linb[c] + acc;
}

// ---------------------------------------------------------------------------
// mel block
// ---------------------------------------------------------------------------
__global__ __launch_bounds__(256) void mel_kernel(
    const float* __restrict__ in, float* __restrict__ out,
    const void* __restrict__ mw, const void* __restrict__ mb,
    int l, const int* __restrict__ flag) {
  const int fl = *flag;
  const int idx = blockIdx.x;
  const int s = (idx & 1) * 256 + threadIdx.x;
  const int c = (idx >> 1) % OUT_;
  const int b = idx / (2 * OUT_);
  const int j = c % 3, i = c / 3;
  float acc = ldr(mb, (l * 3 + j) * 20 + i, fl);
  const long wbase = (long)((l * 3 + j) * 20 + i) * 15;
#pragma unroll
  for (int q = 0; q < 3; ++q) {
    const int ch = 3 * i + q + j - 1;
    if (ch < 0 || ch >= OUT_) continue;
    const float* xr = in + ((long)b * OUT_ + ch) * S_;
#pragma unroll
    for (int k = 0; k < 5; ++k) {
      const int sp = s + k - 2;
      if (sp < 0 || sp >= S_) continue;
      acc += ldr(mw, wbase + q * 5 + k, fl) * xr[sp];
    }
  }
  out[((long)b * OUT_ + c) * S_ + s] = acc + in[((long)b * OUT_ + c) * S_ + s];
}

// ---------------------------------------------------------------------------
// residual grouped conv + transpose to [B][S][60]; store dtype per flag
// ---------------------------------------------------------------------------
__global__ __launch_bounds__(256) void res_kernel(
    const float* __restrict__ lin, const float* __restrict__ mel,
    const void* __restrict__ rw, const void* __restrict__ rb,
    void* __restrict__ outp, const int* __restrict__ flag) {
  const int fl = *flag;
  const int q = threadIdx.x >> 6, lane = threadIdx.x & 63;
  const int bs = blockIdx.x * 4 + q;
  const int b = bs / S_, s = bs % S_;
  if (lane >= OUT_) return;
  const int c = lane;
  float acc = ldr(rb, c, fl);
  const float* x0 = lin + ((long)b * OUT_ + c) * S_;
  const float* x1 = mel + ((long)b * OUT_ + c) * S_;
#pragma unroll
  for (int k = 0; k < 5; ++k) {
    const int sp = s + k - 2;
    if (sp < 0 || sp >= S_) continue;
    acc += ldr(rw, c * 10 + k, fl) * x0[sp] + ldr(rw, c * 10 + 5 + k, fl) * x1[sp];
  }
  const long oi = (long)bs * OUT_ + c;
  if (fl == 0) ((__hip_bfloat16*)outp)[oi] = __float2bfloat16(acc);
  else ((float*)outp)[oi] = acc;
}

// ---------------------------------------------------------------------------
extern "C" void kernel_launch(void* const* d_in, const int* in_sizes, int n_in,
                              void* d_out, int out_size, void* d_ws, size_t ws_size,
                              hipStream_t stream) {
  const void* x    = d_in[0];
  const void* wih0 = d_in[1];
  const void* wihr = d_in[2];
  const void* whh  = d_in[3];
  const void* bih  = d_in[4];
  const void* bhh  = d_in[5];
  const void* linw = d_in[6];
  const void* linb = d_in[7];
  const void* melw = d_in[8];
  const void* melb = d_in[9];
  const void* resw = d_in[10];
  const void* resb = d_in[11];

  float* ws = (float*)d_ws;
  const bool big = ws_size >= 40000000ull;

  unsigned FLAG_O, WF_O, XG_O, H0_O, H1_O, STH_O, STC_O, LIN_O, M1_O, M2_O;
  int TC, tcbits, h_mode;
  if (big) {  // Mode A: TC=128, h fp32 (39.98 MB)
    TC = 128; tcbits = 7; h_mode = 0;
    XG_O = 0u; H0_O = 2949120u; H1_O = 5898240u; WF_O = 8847360u;
    STH_O = 9984300u; STC_O = 9990060u; FLAG_O = 9995820u;
    LIN_O = 0u; M1_O = 983040u; M2_O = 1966080u;
  } else {    // Mode C: TC=32, h bf16 (19.34 MB)
    TC = 32; tcbits = 5; h_mode = 1;
    FLAG_O = 0u; WF_O = 16u; XG_O = 1136956u;
    H0_O = 1874236u; H1_O = 3348796u;
    STH_O = 4823356u; STC_O = 4829116u;
    LIN_O = 10876u; M1_O = 993916u; M2_O = 1976956u;
  }
  int* flag = (int*)(ws + FLAG_O);
  float* wf  = ws + WF_O;
  float* xgc = ws + XG_O;
  float* sth = ws + STH_O;
  float* stc = ws + STC_O;
  float* lin = ws + LIN_O;
  float* m1  = ws + M1_O;
  float* m2  = ws + M2_O;
  void* hbufs[2] = {(void*)(ws + H0_O), (void*)(ws + H1_O)};

  detect_kernel<<<1, 256, 0, stream>>>((const unsigned short*)x, flag);
  prep_kernel<<<(WF_TOT + 255) / 256, 256, 0, stream>>>(
      wih0, wihr, whh, bih, bhh, linw, linb, wf, flag);

  const int NCH = S_ / TC;
  const dim3 ggrid(B_ * TC / 64, 12);
  const void* aprev = nullptr;
  for (int l = 0; l < 4; ++l) {
    const unsigned* wpk_l = (const unsigned*)(wf + WFO_WHH) + (unsigned)l * PKL_;
    const float* bias_l = wf + WFO_BIAS + (unsigned)l * G4_;
    const float* wih_l  = (l == 0) ? (wf + WFO_WIH0)
                                   : (wf + WFO_WIHR + (unsigned)(l - 1) * G4_ * H_);
    const void* a  = (l == 0) ? x : aprev;
    const int a_kind = (l == 0) ? 0 : (h_mode == 0 ? 1 : 2);
    const int K = (l == 0) ? IN_ : H_;
    void* hcur = hbufs[l & 1];
    for (int ch = 0; ch < NCH; ++ch) {
      const int t0 = ch * TC;
      gemm_xg<<<ggrid, 256, 0, stream>>>(a, a_kind, flag, wih_l, bias_l, xgc, K, t0, tcbits);
      lstm_chunk<<<B_, 768, 0, stream>>>(xgc, wpk_l, hcur, h_mode, sth, stc, t0, TC);
    }
    aprev = hcur;
  }

  linear_kernel<<<B_ * OUT_ * 2, 256, 0, stream>>>(
      aprev, h_mode, wf + WFO_LINW, wf + WFO_LINB, lin);

  mel_kernel<<<B_ * OUT_ * 2, 256, 0, stream>>>(lin, m1, melw, melb, 0, flag);
  mel_kernel<<<B_ * OUT_ * 2, 256, 0, stream>>>(m1, m2, melw, melb, 1, flag);
  mel_kernel<<<B_ * OUT_ * 2, 256, 0, stream>>>(m2, m1, melw, melb, 2, flag);

  res_kernel<<<R_ / 4, 256, 0, stream>>>(lin, m1, resw, resb, d_out, flag);
}

// Round 6
// 4250.653 us; speedup vs baseline: 4.6724x; 1.0405x over previous
//
#include <hip/hip_runtime.h>
#include <hip/hip_bf16.h>

#define B_ 32
#define S_ 512
#define IN_ 300
#define H_ 180
#define G4_ 720
#define OUT_ 60
#define R_ 16384   // B_*S_
#define NPK_ 92    // f16-pair regs per thread (90 data + 2 zero pad)

// Unified fp32 weight-region sub-offsets (floats from wf base):
//   [linw 10800][linb 60][wih0 216000][wihr 388800][whh-region 518400][bias 2880]
//   whh-region holds PACKED f16-pair whh^T: [l][92][720] uints (264,960), rest 0.
#define WFO_LINW 0u
#define WFO_LINB 10800u
#define WFO_WIH0 10860u
#define WFO_WIHR 226860u
#define WFO_WHH  615660u
#define WFO_BIAS 1134060u
#define WF_TOT   1136940u
#define PKL_ (NPK_ * G4_)   // 66,240 uints per layer

#if defined(__has_builtin)
#if __has_builtin(__builtin_amdgcn_fdot2)
#define HAVE_FDOT2 1
#endif
#endif

typedef _Float16 f16x2 __attribute__((ext_vector_type(2)));

__device__ __forceinline__ float sigf(float x)   { return 1.f / (1.f + __expf(-x)); }
__device__ __forceinline__ float tanhf2(float x) { return 2.f / (1.f + __expf(-2.f * x)) - 1.f; }
__device__ __forceinline__ float toF(__hip_bfloat16 x) { return __bfloat162float(x); }
__device__ __forceinline__ float ldr(const void* p, long i, int fl) {
  return fl ? ((const float*)p)[i] : toF(((const __hip_bfloat16*)p)[i]);
}
__device__ __forceinline__ unsigned f16b(_Float16 h) {
  union { _Float16 f; unsigned short s; } x; x.f = h; return x.s;
}
__device__ __forceinline__ float h2f(unsigned s) {
  union { unsigned short s; _Float16 f; } x; x.s = (unsigned short)(s & 0xFFFFu);
  return (float)x.f;
}
__device__ __forceinline__ f16x2 u2h(unsigned u) {
  union { unsigned u; f16x2 v; } x; x.u = u; return x.v;
}

// ---------------------------------------------------------------------------
// detect: bf16 vs fp32 raw inputs via exponent stats of x's first 2048 words
// ---------------------------------------------------------------------------
__global__ __launch_bounds__(256) void detect_kernel(
    const unsigned short* __restrict__ xw, int* __restrict__ flag) {
  __shared__ int cnt;
  if (threadIdx.x == 0) cnt = 0;
  __syncthreads();
  int lc = 0;
  for (int i = threadIdx.x; i < 2048; i += 256) {
    const int e = (xw[i] >> 7) & 0xFF;
    if (e >= 0xC0 || (e > 0 && e < 0x40)) lc++;
  }
  atomicAdd(&cnt, lc);
  __syncthreads();
  if (threadIdx.x == 0) *flag = (cnt > 100) ? 1 : 0;
}

// ---------------------------------------------------------------------------
// prep: raw weights -> ws. whh packed as f16 pairs transposed [l][jp][o]
// (pair jp = k's 2jp,2jp+1; jp>=90 zero). Others fp32. bias = bih+bhh.
// ---------------------------------------------------------------------------
__global__ __launch_bounds__(256) void prep_kernel(
    const void* __restrict__ wih0, const void* __restrict__ wihr,
    const void* __restrict__ whh,  const void* __restrict__ bih,
    const void* __restrict__ bhh,  const void* __restrict__ linw,
    const void* __restrict__ linb, float* __restrict__ wf,
    const int* __restrict__ flag) {
  const unsigned i = blockIdx.x * 256u + threadIdx.x;
  if (i >= WF_TOT) return;
  const int fl = *flag;
  if (i >= WFO_WHH && i < WFO_BIAS) {
    const unsigned j = i - WFO_WHH;
    unsigned u = 0u;
    if (j < 4u * PKL_) {
      const unsigned l = j / PKL_, r = j - l * PKL_;
      const unsigned jp = r / G4_, o = r - jp * G4_;
      if (jp < 90u) {
        const long base = (long)l * 129600 + (long)o * H_;
        const _Float16 w0 = (_Float16)ldr(whh, base + 2 * jp, fl);
        const _Float16 w1 = (_Float16)ldr(whh, base + 2 * jp + 1, fl);
        u = f16b(w0) | (f16b(w1) << 16);
      }
    }
    ((unsigned*)wf)[i] = u;
    return;
  }
  float v;
  if (i < WFO_LINB)            v = ldr(linw, i, fl);
  else if (i < WFO_WIH0)       v = ldr(linb, i - WFO_LINB, fl);
  else if (i < WFO_WIHR)       v = ldr(wih0, i - WFO_WIH0, fl);
  else if (i < WFO_WHH)        v = ldr(wihr, i - WFO_WIHR, fl);
  else { const unsigned j = i - WFO_BIAS; v = ldr(bih, j, fl) + ldr(bhh, j, fl); }
  wf[i] = v;
}

// ---------------------------------------------------------------------------
// fused_kernel: blocks [0,nlstm) run the LSTM recurrence for the CURRENT
// chunk; remaining blocks compute the NEXT chunk's input projection
// (3 x 64x64 tiles per 768-thread block). The two halves touch disjoint
// buffers; stream-serialized launches provide cross-launch ordering.
//   lstm: Whh register-resident as 92 packed f16 pairs, pinned via asm so
//   the backend cannot rematerialize the (provably invariant) loads.
//   gemm: ntiles is 0 or a multiple of 3 -> block-uniform early exit.
// ---------------------------------------------------------------------------
__global__ __launch_bounds__(768, 3) void fused_kernel(
    // lstm part
    const float* __restrict__ xg, const unsigned* __restrict__ wpk,
    void* __restrict__ hout, int h_mode,
    float* __restrict__ st_h, float* __restrict__ st_c,
    int t0, int TC, int nlstm,
    // gemm part
    const void* __restrict__ ga, int a_kind, const int* __restrict__ flag,
    const float* __restrict__ gW, const float* __restrict__ gbias,
    float* __restrict__ xgn, int gK, int gt0, int tcbits, int ntiles) {
  __shared__ __align__(16) unsigned hpk_hi[NPK_];
  __shared__ __align__(16) unsigned hpk_lo[NPK_];
  __shared__ float gbuf[G4_];
  __shared__ __align__(16) float Ast[3][20][68];
  __shared__ __align__(16) float Bst[3][20][68];

  const int bid = blockIdx.x;
  if (bid < nlstm) {
    // ---------------- LSTM body ----------------
    const int b = bid;
    const int o = threadIdx.x;
    const bool act = o < G4_;
    unsigned w[NPK_];
    if (act) {
#pragma unroll
      for (int j = 0; j < NPK_; ++j) {
        w[j] = wpk[j * G4_ + o];
        asm volatile("" : "+v"(w[j]));   // pin: loop consumes asm output -> no remat
      }
    }
    float c = 0.f;
    if (o == 180 || o == 181) { hpk_hi[o - 90] = 0u; hpk_lo[o - 90] = 0u; }
    if (o < H_) {
      float h = 0.f;
      if (t0 != 0) { h = st_h[b * H_ + o]; c = st_c[b * H_ + o]; }
      const _Float16 hh = (_Float16)h;
      const _Float16 hl = (_Float16)(h - (float)hh);
      const unsigned v = f16b(hh) | (f16b(hl) << 16);
      const unsigned nx = __shfl_down(v, 1);
      if ((o & 1) == 0) {
        hpk_hi[o >> 1] = (v & 0xFFFFu) | ((nx & 0xFFFFu) << 16);
        hpk_lo[o >> 1] = (v >> 16) | (nx & 0xFFFF0000u);
      }
    }
    const float* xgp = xg + (long)b * TC * G4_ + o;
    float xcur = act ? xgp[0] : 0.f;
    __syncthreads();
    for (int tl = 0; tl < TC; ++tl) {
      if (act) {
        float a0 = xcur, a1 = 0.f, a2 = 0.f, a3 = 0.f;
#pragma unroll
        for (int j4 = 0; j4 < NPK_ / 4; ++j4) {
          const uint4 hh = *(const uint4*)&hpk_hi[j4 * 4];
          const uint4 hl = *(const uint4*)&hpk_lo[j4 * 4];
#ifdef HAVE_FDOT2
          a0 = __builtin_amdgcn_fdot2(u2h(hh.x), u2h(w[j4 * 4 + 0]), a0, false);
          a1 = __builtin_amdgcn_fdot2(u2h(hh.y), u2h(w[j4 * 4 + 1]), a1, false);
          a2 = __builtin_amdgcn_fdot2(u2h(hh.z), u2h(w[j4 * 4 + 2]), a2, false);
          a3 = __builtin_amdgcn_fdot2(u2h(hh.w), u2h(w[j4 * 4 + 3]), a3, false);
          a0 = __builtin_amdgcn_fdot2(u2h(hl.x), u2h(w[j4 * 4 + 0]), a0, false);
          a1 = __builtin_amdgcn_fdot2(u2h(hl.y), u2h(w[j4 * 4 + 1]), a1, false);
          a2 = __builtin_amdgcn_fdot2(u2h(hl.z), u2h(w[j4 * 4 + 2]), a2, false);
          a3 = __builtin_amdgcn_fdot2(u2h(hl.w), u2h(w[j4 * 4 + 3]), a3, false);
#else
          const unsigned w0 = w[j4 * 4 + 0], w1 = w[j4 * 4 + 1];
          const unsigned w2 = w[j4 * 4 + 2], w3 = w[j4 * 4 + 3];
          a0 += (h2f(hh.x) + h2f(hl.x)) * h2f(w0) +
                (h2f(hh.x >> 16) + h2f(hl.x >> 16)) * h2f(w0 >> 16);
          a1 += (h2f(hh.y) + h2f(hl.y)) * h2f(w1) +
                (h2f(hh.y >> 16) + h2f(hl.y >> 16)) * h2f(w1 >> 16);
          a2 += (h2f(hh.z) + h2f(hl.z)) * h2f(w2) +
                (h2f(hh.z >> 16) + h2f(hl.z >> 16)) * h2f(w2 >> 16);
          a3 += (h2f(hh.w) + h2f(hl.w)) * h2f(w3) +
                (h2f(hh.w >> 16) + h2f(hl.w >> 16)) * h2f(w3 >> 16);
#endif
        }
        const float acc = (a0 + a1) + (a2 + a3);
        const bool isg = (o >= 2 * H_) && (o < 3 * H_);
        gbuf[o] = isg ? tanhf2(acc) : sigf(acc);
        const int tn = (tl + 1 < TC) ? tl + 1 : tl;   // prefetch next xg
        xcur = xgp[(long)tn * G4_];
      }
      __syncthreads();
      if (o < H_) {
        c = gbuf[H_ + o] * c + gbuf[o] * gbuf[2 * H_ + o];
        const float h = gbuf[3 * H_ + o] * tanhf2(c);
        const long gi = ((long)b * S_ + t0 + tl) * H_ + o;
        if (h_mode == 0) ((float*)hout)[gi] = h;
        else ((__hip_bfloat16*)hout)[gi] = __float2bfloat16(h);
        const _Float16 hh2 = (_Float16)h;
        const _Float16 hl2 = (_Float16)(h - (float)hh2);
        const unsigned v = f16b(hh2) | (f16b(hl2) << 16);
        const unsigned nx = __shfl_down(v, 1);
        if ((o & 1) == 0) {
          hpk_hi[o >> 1] = (v & 0xFFFFu) | ((nx & 0xFFFFu) << 16);
          hpk_lo[o >> 1] = (v >> 16) | (nx & 0xFFFF0000u);
        }
        if (tl == TC - 1) { st_h[b * H_ + o] = h; st_c[b * H_ + o] = c; }
      }
      __syncthreads();
    }
    return;
  }

  // ---------------- GEMM body (next chunk's xg) ----------------
  if ((bid - nlstm) * 3 >= ntiles) return;  // block-uniform (ntiles % 3 == 0)
  const int g = threadIdx.x >> 8, t = threadIdx.x & 255;
  const int ti = (bid - nlstm) * 3 + g;
  const int nrt = (B_ * TC) >> 6;           // row tiles in the chunk
  const int rt = ti % nrt, ct = ti / nrt;
  const int rho0 = rt << 6, o0 = ct << 6;
  const int tx = t & 15, ty = t >> 4;
  const int fl = *flag;
  const int tcm = (1 << tcbits) - 1;
  float acc[4][4] = {};
  for (int k0 = 0; k0 < gK; k0 += 20) {
    for (int e = t; e < 1280; e += 256) {
      const int rl = e / 20, kk = e % 20;
      const int rho = rho0 + rl;
      const int bb = rho >> tcbits, tl = rho & tcm;
      const long gi = ((long)bb * S_ + gt0 + tl) * gK + k0 + kk;
      float av;
      if (a_kind == 1)      av = ((const float*)ga)[gi];
      else if (a_kind == 2) av = toF(((const __hip_bfloat16*)ga)[gi]);
      else                  av = ldr(ga, gi, fl);
      Ast[g][kk][rl] = av;
      const int o = o0 + rl;
      Bst[g][kk][rl] = (o < G4_) ? gW[(long)o * gK + k0 + kk] : 0.f;
    }
    __syncthreads();
#pragma unroll
    for (int kk = 0; kk < 20; ++kk) {
      const float4 a4 = *(const float4*)&Ast[g][kk][ty * 4];
      const float4 b4 = *(const float4*)&Bst[g][kk][tx * 4];
      const float av[4] = {a4.x, a4.y, a4.z, a4.w};
      const float bv[4] = {b4.x, b4.y, b4.z, b4.w};
#pragma unroll
      for (int i = 0; i < 4; ++i)
#pragma unroll
        for (int j = 0; j < 4; ++j) acc[i][j] += av[i] * bv[j];
    }
    __syncthreads();
  }
#pragma unroll
  for (int i = 0; i < 4; ++i) {
    const int rho = rho0 + ty * 4 + i;
#pragma unroll
    for (int j = 0; j < 4; ++j) {
      const int o = o0 + tx * 4 + j;
      if (o < G4_) xgn[(long)rho * G4_ + o] = acc[i][j] + gbias[o];
    }
  }
}

// ---------------------------------------------------------------------------
// linear: lin[b][c][s] = h[(b,s)] . linW[c] + linb[c]
// ---------------------------------------------------------------------------
__global__ __launch_bounds__(256) void linear_kernel(
    const void* __restrict__ h, int h_mode, const float* __restrict__ linw,
    const float* __restrict__ linb, float* __restrict__ out) {
  const int idx = blockIdx.x;
  const int s = (idx & 1) * 256 + threadIdx.x;
  const int c = (idx >> 1) % OUT_;
  const int b = idx / (2 * OUT_);
  const long hbase = ((long)b * S_ + s) * H_;
  const float* wr = linw + (long)c * H_;
  float acc = 0.f;
  if (h_mode == 0) {
    const float* hr = (const float*)h + hbase;
    float a0 = 0.f, a1 = 0.f, a2 = 0.f, a3 = 0.f;
#pragma unroll 9
    for (int k4 = 0; k4 < 45; ++k4) {
      const float4 hv = *(const float4*)(hr + k4 * 4);
      const float4 wv = *(const float4*)(wr + k4 * 4);
      a0 += hv.x * wv.x; a1 += hv.y * wv.y; a2 += hv.z * wv.z; a3 += hv.w * wv.w;
    }
    acc = ((a0 + a1) + (a2 + a3));
  } else {
    const __hip_bfloat16* hr = (const __hip_bfloat16*)h + hbase;
#pragma unroll 4
    for (int k = 0; k < H_; ++k) acc += toF(hr[k]) * wr[k];
  }
  out[((long)b * OUT_ + c) * S_ + s] = linb[c] + acc;
}

// ---------------------------------------------------------------------------
// mel block
// ---------------------------------------------------------------------------
__global__ __launch_bounds__(256) void mel_kernel(
    const float* __restrict__ in, float* __restrict__ out,
    const void* __restrict__ mw, const void* __restrict__ mb,
    int l, const int* __restrict__ flag) {
  const int fl = *flag;
  const int idx = blockIdx.x;
  const int s = (idx & 1) * 256 + threadIdx.x;
  const int c = (idx >> 1) % OUT_;
  const int b = idx / (2 * OUT_);
  const int j = c % 3, i = c / 3;
  float acc = ldr(mb, (l * 3 + j) * 20 + i, fl);
  const long wbase = (long)((l * 3 + j) * 20 + i) * 15;
#pragma unroll
  for (int q = 0; q < 3; ++q) {
    const int ch = 3 * i + q + j - 1;
    if (ch < 0 || ch >= OUT_) continue;
    const float* xr = in + ((long)b * OUT_ + ch) * S_;
#pragma unroll
    for (int k = 0; k < 5; ++k) {
      const int sp = s + k - 2;
      if (sp < 0 || sp >= S_) continue;
      acc += ldr(mw, wbase + q * 5 + k, fl) * xr[sp];
    }
  }
  out[((long)b * OUT_ + c) * S_ + s] = acc + in[((long)b * OUT_ + c) * S_ + s];
}

// ---------------------------------------------------------------------------
// residual grouped conv + transpose to [B][S][60]; store dtype per flag
// ---------------------------------------------------------------------------
__global__ __launch_bounds__(256) void res_kernel(
    const float* __restrict__ lin, const float* __restrict__ mel,
    const void* __restrict__ rw, const void* __restrict__ rb,
    void* __restrict__ outp, const int* __restrict__ flag) {
  const int fl = *flag;
  const int q = threadIdx.x >> 6, lane = threadIdx.x & 63;
  const int bs = blockIdx.x * 4 + q;
  const int b = bs / S_, s = bs % S_;
  if (lane >= OUT_) return;
  const int c = lane;
  float acc = ldr(rb, c, fl);
  const float* x0 = lin + ((long)b * OUT_ + c) * S_;
  const float* x1 = mel + ((long)b * OUT_ + c) * S_;
#pragma unroll
  for (int k = 0; k < 5; ++k) {
    const int sp = s + k - 2;
    if (sp < 0 || sp >= S_) continue;
    acc += ldr(rw, c * 10 + k, fl) * x0[sp] + ldr(rw, c * 10 + 5 + k, fl) * x1[sp];
  }
  const long oi = (long)bs * OUT_ + c;
  if (fl == 0) ((__hip_bfloat16*)outp)[oi] = __float2bfloat16(acc);
  else ((float*)outp)[oi] = acc;
}

// ---------------------------------------------------------------------------
extern "C" void kernel_launch(void* const* d_in, const int* in_sizes, int n_in,
                              void* d_out, int out_size, void* d_ws, size_t ws_size,
                              hipStream_t stream) {
  const void* x    = d_in[0];
  const void* wih0 = d_in[1];
  const void* wihr = d_in[2];
  const void* whh  = d_in[3];
  const void* bih  = d_in[4];
  const void* bhh  = d_in[5];
  const void* linw = d_in[6];
  const void* linb = d_in[7];
  const void* melw = d_in[8];
  const void* melb = d_in[9];
  const void* resw = d_in[10];
  const void* resb = d_in[11];

  float* ws = (float*)d_ws;
  const bool big = ws_size >= 40000000ull;

  unsigned FLAG_O, WF_O, XG0_O, XG1_O, H0_O, H1_O, STH_O, STC_O, LIN_O, M1_O, M2_O;
  int h_mode;
  if (big) {  // Mode A: TC=64 double-buffered xg, h fp32 (39.98 MB)
    h_mode = 0;
    XG0_O = 0u; XG1_O = 1474560u;              // 2 x [2048][720]
    H0_O = 2949120u; H1_O = 5898240u; WF_O = 8847360u;
    STH_O = 9984300u; STC_O = 9990060u; FLAG_O = 9995820u;
    LIN_O = 0u; M1_O = 983040u; M2_O = 1966080u;
  } else {    // Mode C: TC=32 single xg, h bf16 (19.34 MB), sequential
    h_mode = 1;
    FLAG_O = 0u; WF_O = 16u; XG0_O = 1136956u; XG1_O = 1136956u;
    H0_O = 1874236u; H1_O = 3348796u;
    STH_O = 4823356u; STC_O = 4829116u;
    LIN_O = 10876u; M1_O = 993916u; M2_O = 1976956u;
  }
  int* flag = (int*)(ws + FLAG_O);
  float* wf  = ws + WF_O;
  float* sth = ws + STH_O;
  float* stc = ws + STC_O;
  float* lin = ws + LIN_O;
  float* m1  = ws + M1_O;
  float* m2  = ws + M2_O;
  float* xgb[2] = {ws + XG0_O, ws + XG1_O};
  void* hbufs[2] = {(void*)(ws + H0_O), (void*)(ws + H1_O)};
  const unsigned* wpk = (const unsigned*)(wf + WFO_WHH);

  detect_kernel<<<1, 256, 0, stream>>>((const unsigned short*)x, flag);
  prep_kernel<<<(WF_TOT + 255) / 256, 256, 0, stream>>>(
      wih0, wihr, whh, bih, bhh, linw, linb, wf, flag);

  const void* afinal;
  if (big) {
    // prologue: gemm-only for global chunk 0 (layer 0, t0=0)
    fused_kernel<<<160, 768, 0, stream>>>(
        xgb[0], wpk, hbufs[0], 0, sth, stc, 0, 64, /*nlstm=*/0,
        x, 0, flag, wf + WFO_WIH0, wf + WFO_BIAS, xgb[0], IN_, 0, 6, 384);
    for (int gc = 0; gc < 32; ++gc) {
      const int l = gc >> 3, ch = gc & 7;
      const int gcn = gc + 1;
      const int ln = gcn >> 3, chn = gcn & 7;
      const int ntiles = (gc == 31) ? 0 : 384;
      const void* ga; int ak; const float* gW; const float* gb2; float* xgn;
      int gK, gt0;
      if (gc == 31) {  // dead args for the gemm side
        ga = x; ak = 0; gW = wf + WFO_WIH0; gb2 = wf + WFO_BIAS;
        xgn = xgb[0]; gK = IN_; gt0 = 0;
      } else {
        ga = (ln == 0) ? x : (const void*)hbufs[(ln - 1) & 1];
        ak = (ln == 0) ? 0 : 1;
        gW = (ln == 0) ? (wf + WFO_WIH0)
                       : (wf + WFO_WIHR + (unsigned)(ln - 1) * G4_ * H_);
        gb2 = wf + WFO_BIAS + (unsigned)ln * G4_;
        xgn = xgb[gcn & 1]; gK = (ln == 0) ? IN_ : H_; gt0 = chn * 64;
      }
      fused_kernel<<<160, 768, 0, stream>>>(
          xgb[gc & 1], wpk + (unsigned)l * PKL_, hbufs[l & 1], 0,
          sth, stc, ch * 64, 64, 32,
          ga, ak, flag, gW, gb2, xgn, gK, gt0, 6, ntiles);
    }
    afinal = hbufs[1];  // layer 3
  } else {
    // sequential fallback: gemm-only then lstm-only per TC=32 chunk
    const void* aprev = nullptr;
    for (int l = 0; l < 4; ++l) {
      const unsigned* wpk_l = wpk + (unsigned)l * PKL_;
      const float* bias_l = wf + WFO_BIAS + (unsigned)l * G4_;
      const float* wih_l  = (l == 0) ? (wf + WFO_WIH0)
                                     : (wf + WFO_WIHR + (unsigned)(l - 1) * G4_ * H_);
      const void* a  = (l == 0) ? x : aprev;
      const int ak = (l == 0) ? 0 : 2;
      const int K = (l == 0) ? IN_ : H_;
      void* hcur = hbufs[l & 1];
      for (int ch = 0; ch < 16; ++ch) {
        fused_kernel<<<64, 768, 0, stream>>>(
            xgb[0], wpk_l, hcur, 1, sth, stc, 0, 32, 0,
            a, ak, flag, wih_l, bias_l, xgb[0], K, ch * 32, 5, 192);
        fused_kernel<<<32, 768, 0, stream>>>(
            xgb[0], wpk_l, hcur, 1, sth, stc, ch * 32, 32, 32,
            x, 0, flag, wf + WFO_WIH0, wf + WFO_BIAS, xgb[0], IN_, 0, 5, 0);
      }
      aprev = hcur;
    }
    afinal = hbufs[1];
  }

  linear_kernel<<<B_ * OUT_ * 2, 256, 0, stream>>>(
      afinal, h_mode, wf + WFO_LINW, wf + WFO_LINB, lin);

  mel_kernel<<<B_ * OUT_ * 2, 256, 0, stream>>>(lin, m1, melw, melb, 0, flag);
  mel_kernel<<<B_ * OUT_ * 2, 256, 0, stream>>>(m1, m2, melw, melb, 1, flag);
  mel_kernel<<<B_ * OUT_ * 2, 256, 0, stream>>>(m2, m1, melw, melb, 2, flag);

  res_kernel<<<R_ / 4, 256, 0, stream>>>(lin, m1, resw, resb, d_out, flag);
}

// Round 7
// 3839.759 us; speedup vs baseline: 5.1724x; 1.1070x over previous
//
#include <hip/hip_runtime.h>
#include <hip/hip_bf16.h>

#define B_ 32
#define S_ 512
#define IN_ 300
#define H_ 180
#define G4_ 720
#define OUT_ 60
#define R_ 16384   // B_*S_
#define NPK_ 92    // f16-pair regs per thread (90 data + 2 zero pad)

// Unified fp32 weight-region sub-offsets (floats from wf base):
//   [linw 10800][linb 60][wih0 216000][wihr 388800][whh-region 518400][bias 2880]
//   whh-region holds PACKED f16-pair whh^T: [l][jp][o] uints (jp<92, o<720).
#define WFO_LINW 0u
#define WFO_LINB 10800u
#define WFO_WIH0 10860u
#define WFO_WIHR 226860u
#define WFO_WHH  615660u
#define WFO_BIAS 1134060u
#define WF_TOT   1136940u
#define PKL_ (NPK_ * G4_)   // 66,240 uints per layer

#if defined(__has_builtin)
#if __has_builtin(__builtin_amdgcn_fdot2)
#define HAVE_FDOT2 1
#endif
#endif

typedef _Float16 f16x2 __attribute__((ext_vector_type(2)));

__device__ __forceinline__ float sigf(float x)   { return 1.f / (1.f + __expf(-x)); }
__device__ __forceinline__ float tanhf2(float x) { return 2.f / (1.f + __expf(-2.f * x)) - 1.f; }
__device__ __forceinline__ float toF(__hip_bfloat16 x) { return __bfloat162float(x); }
__device__ __forceinline__ float ldr(const void* p, long i, int fl) {
  return fl ? ((const float*)p)[i] : toF(((const __hip_bfloat16*)p)[i]);
}
__device__ __forceinline__ unsigned f16b(_Float16 h) {
  union { _Float16 f; unsigned short s; } x; x.f = h; return x.s;
}
__device__ __forceinline__ float h2f(unsigned s) {
  union { unsigned short s; _Float16 f; } x; x.s = (unsigned short)(s & 0xFFFFu);
  return (float)x.f;
}
__device__ __forceinline__ f16x2 u2h(unsigned u) {
  union { unsigned u; f16x2 v; } x; x.u = u; return x.v;
}
__device__ __forceinline__ float fd2(unsigned hu, unsigned wu, float acc) {
#ifdef HAVE_FDOT2
  return __builtin_amdgcn_fdot2(u2h(hu), u2h(wu), acc, false);
#else
  return acc + h2f(hu) * h2f(wu) + h2f(hu >> 16) * h2f(wu >> 16);
#endif
}

// 23 groups x 4 packed weight words = 92 named scalars (no array -> SROA-proof)
#define REP23(M) M(0) M(1) M(2) M(3) M(4) M(5) M(6) M(7) M(8) M(9) M(10) \
  M(11) M(12) M(13) M(14) M(15) M(16) M(17) M(18) M(19) M(20) M(21) M(22)
#define LW(n) \
  unsigned w##n##a = wp0[(4*n+0)*G4_], w##n##b = wp0[(4*n+1)*G4_], \
           w##n##c = wp0[(4*n+2)*G4_], w##n##d = wp0[(4*n+3)*G4_];
#define PW(n) \
  asm volatile("" : "+v"(w##n##a), "+v"(w##n##b), "+v"(w##n##c), "+v"(w##n##d));
#define ST(n) { \
  const uint4 hh = *(const uint4*)&hpk_hi[4*n]; \
  const uint4 hl = *(const uint4*)&hpk_lo[4*n]; \
  a0 = fd2(hh.x, w##n##a, a0); a1 = fd2(hh.y, w##n##b, a1); \
  a2 = fd2(hh.z, w##n##c, a2); a3 = fd2(hh.w, w##n##d, a3); \
  a0 = fd2(hl.x, w##n##a, a0); a1 = fd2(hl.y, w##n##b, a1); \
  a2 = fd2(hl.z, w##n##c, a2); a3 = fd2(hl.w, w##n##d, a3); }

// ---------------------------------------------------------------------------
// detect: bf16 vs fp32 raw inputs via exponent stats of x's first 2048 words
// ---------------------------------------------------------------------------
__global__ __launch_bounds__(256) void detect_kernel(
    const unsigned short* __restrict__ xw, int* __restrict__ flag) {
  __shared__ int cnt;
  if (threadIdx.x == 0) cnt = 0;
  __syncthreads();
  int lc = 0;
  for (int i = threadIdx.x; i < 2048; i += 256) {
    const int e = (xw[i] >> 7) & 0xFF;
    if (e >= 0xC0 || (e > 0 && e < 0x40)) lc++;
  }
  atomicAdd(&cnt, lc);
  __syncthreads();
  if (threadIdx.x == 0) *flag = (cnt > 100) ? 1 : 0;
}

// ---------------------------------------------------------------------------
// prep: raw weights -> ws. whh packed as f16 pairs transposed [l][jp][o]
// (pair jp = k's 2jp,2jp+1; jp>=90 zero). Others fp32. bias = bih+bhh.
// ---------------------------------------------------------------------------
__global__ __launch_bounds__(256) void prep_kernel(
    const void* __restrict__ wih0, const void* __restrict__ wihr,
    const void* __restrict__ whh,  const void* __restrict__ bih,
    const void* __restrict__ bhh,  const void* __restrict__ linw,
    const void* __restrict__ linb, float* __restrict__ wf,
    const int* __restrict__ flag) {
  const unsigned i = blockIdx.x * 256u + threadIdx.x;
  if (i >= WF_TOT) return;
  const int fl = *flag;
  if (i >= WFO_WHH && i < WFO_BIAS) {
    const unsigned j = i - WFO_WHH;
    unsigned u = 0u;
    if (j < 4u * PKL_) {
      const unsigned l = j / PKL_, r = j - l * PKL_;
      const unsigned jp = r / G4_, o = r - jp * G4_;
      if (jp < 90u) {
        const long base = (long)l * 129600 + (long)o * H_;
        const _Float16 w0 = (_Float16)ldr(whh, base + 2 * jp, fl);
        const _Float16 w1 = (_Float16)ldr(whh, base + 2 * jp + 1, fl);
        u = f16b(w0) | (f16b(w1) << 16);
      }
    }
    ((unsigned*)wf)[i] = u;
    return;
  }
  float v;
  if (i < WFO_LINB)            v = ldr(linw, i, fl);
  else if (i < WFO_WIH0)       v = ldr(linb, i - WFO_LINB, fl);
  else if (i < WFO_WIHR)       v = ldr(wih0, i - WFO_WIH0, fl);
  else if (i < WFO_WHH)        v = ldr(wihr, i - WFO_WIHR, fl);
  else { const unsigned j = i - WFO_BIAS; v = ldr(bih, j, fl) + ldr(bhh, j, fl); }
  wf[i] = v;
}

// ---------------------------------------------------------------------------
// fused_kernel: blocks [0,nlstm) run the LSTM recurrence for the CURRENT
// chunk; remaining blocks compute the NEXT chunk's input projection.
//   lstm: Whh register-resident as 92 NAMED-SCALAR packed f16 pairs (asm
//   pinned; no array -> no SROA failure -> no scratch).
// ---------------------------------------------------------------------------
__global__ __launch_bounds__(768, 3) void fused_kernel(
    // lstm part
    const float* __restrict__ xg, const unsigned* __restrict__ wpk,
    void* __restrict__ hout, int h_mode,
    float* __restrict__ st_h, float* __restrict__ st_c,
    int t0, int TC, int nlstm,
    // gemm part
    const void* __restrict__ ga, int a_kind, const int* __restrict__ flag,
    const float* __restrict__ gW, const float* __restrict__ gbias,
    float* __restrict__ xgn, int gK, int gt0, int tcbits, int ntiles) {
  __shared__ __align__(16) unsigned hpk_hi[NPK_];
  __shared__ __align__(16) unsigned hpk_lo[NPK_];
  __shared__ float gbuf[G4_];
  __shared__ __align__(16) float Ast[3][20][68];
  __shared__ __align__(16) float Bst[3][20][68];

  const int bid = blockIdx.x;
  if (bid < nlstm) {
    // ---------------- LSTM body ----------------
    const int b = bid;
    const int o = threadIdx.x;
    const bool act = o < G4_;
    const int oc = act ? o : 0;
    const unsigned* wp0 = wpk + oc;
    REP23(LW)                 // 92 coalesced one-time loads
    REP23(PW)                 // pin each named scalar in a VGPR
    float c = 0.f;
    if (o == 180 || o == 181) { hpk_hi[o - 90] = 0u; hpk_lo[o - 90] = 0u; }
    if (o < H_) {
      float h = 0.f;
      if (t0 != 0) { h = st_h[b * H_ + o]; c = st_c[b * H_ + o]; }
      const _Float16 hh = (_Float16)h;
      const _Float16 hl = (_Float16)(h - (float)hh);
      const unsigned v = f16b(hh) | (f16b(hl) << 16);
      const unsigned nx = __shfl_down(v, 1);
      if ((o & 1) == 0) {
        hpk_hi[o >> 1] = (v & 0xFFFFu) | ((nx & 0xFFFFu) << 16);
        hpk_lo[o >> 1] = (v >> 16) | (nx & 0xFFFF0000u);
      }
    }
    const float* xgp = xg + (long)b * TC * G4_ + oc;
    float xcur = xgp[0];
    __syncthreads();
    for (int tl = 0; tl < TC; ++tl) {
      {
        float a0 = xcur, a1 = 0.f, a2 = 0.f, a3 = 0.f;
        REP23(ST)
        const float acc = (a0 + a1) + (a2 + a3);
        const bool isg = (o >= 2 * H_) && (o < 3 * H_);
        if (act) gbuf[o] = isg ? tanhf2(acc) : sigf(acc);
        const int tn = (tl + 1 < TC) ? tl + 1 : tl;   // prefetch next xg
        xcur = xgp[(long)tn * G4_];
      }
      __syncthreads();
      if (o < H_) {
        c = gbuf[H_ + o] * c + gbuf[o] * gbuf[2 * H_ + o];
        const float h = gbuf[3 * H_ + o] * tanhf2(c);
        const long gi = ((long)b * S_ + t0 + tl) * H_ + o;
        if (h_mode == 0) ((float*)hout)[gi] = h;
        else ((__hip_bfloat16*)hout)[gi] = __float2bfloat16(h);
        const _Float16 hh2 = (_Float16)h;
        const _Float16 hl2 = (_Float16)(h - (float)hh2);
        const unsigned v = f16b(hh2) | (f16b(hl2) << 16);
        const unsigned nx = __shfl_down(v, 1);
        if ((o & 1) == 0) {
          hpk_hi[o >> 1] = (v & 0xFFFFu) | ((nx & 0xFFFFu) << 16);
          hpk_lo[o >> 1] = (v >> 16) | (nx & 0xFFFF0000u);
        }
        if (tl == TC - 1) { st_h[b * H_ + o] = h; st_c[b * H_ + o] = c; }
      }
      __syncthreads();
    }
    return;
  }

  // ---------------- GEMM body (next chunk's xg) ----------------
  if ((bid - nlstm) * 3 >= ntiles) return;  // block-uniform (ntiles % 3 == 0)
  const int g = threadIdx.x >> 8, t = threadIdx.x & 255;
  const int ti = (bid - nlstm) * 3 + g;
  const int nrt = (B_ * TC) >> 6;           // row tiles in the chunk
  const int rt = ti % nrt, ct = ti / nrt;
  const int rho0 = rt << 6, o0 = ct << 6;
  const int tx = t & 15, ty = t >> 4;
  const int fl = *flag;
  const int tcm = (1 << tcbits) - 1;
  float acc[4][4] = {};
  for (int k0 = 0; k0 < gK; k0 += 20) {
    for (int e = t; e < 1280; e += 256) {
      const int rl = e / 20, kk = e % 20;
      const int rho = rho0 + rl;
      const int bb = rho >> tcbits, tl = rho & tcm;
      const long gi = ((long)bb * S_ + gt0 + tl) * gK + k0 + kk;
      float av;
      if (a_kind == 1)      av = ((const float*)ga)[gi];
      else if (a_kind == 2) av = toF(((const __hip_bfloat16*)ga)[gi]);
      else                  av = ldr(ga, gi, fl);
      Ast[g][kk][rl] = av;
      const int o = o0 + rl;
      Bst[g][kk][rl] = (o < G4_) ? gW[(long)o * gK + k0 + kk] : 0.f;
    }
    __syncthreads();
#pragma unroll
    for (int kk = 0; kk < 20; ++kk) {
      const float4 a4 = *(const float4*)&Ast[g][kk][ty * 4];
      const float4 b4 = *(const float4*)&Bst[g][kk][tx * 4];
      const float av[4] = {a4.x, a4.y, a4.z, a4.w};
      const float bv[4] = {b4.x, b4.y, b4.z, b4.w};
#pragma unroll
      for (int i = 0; i < 4; ++i)
#pragma unroll
        for (int j = 0; j < 4; ++j) acc[i][j] += av[i] * bv[j];
    }
    __syncthreads();
  }
#pragma unroll
  for (int i = 0; i < 4; ++i) {
    const int rho = rho0 + ty * 4 + i;
#pragma unroll
    for (int j = 0; j < 4; ++j) {
      const int o = o0 + tx * 4 + j;
      if (o < G4_) xgn[(long)rho * G4_ + o] = acc[i][j] + gbias[o];
    }
  }
}

// ---------------------------------------------------------------------------
// linear: lin[b][c][s] = h[(b,s)] . linW[c] + linb[c]
// ---------------------------------------------------------------------------
__global__ __launch_bounds__(256) void linear_kernel(
    const void* __restrict__ h, int h_mode, const float* __restrict__ linw,
    const float* __restrict__ linb, float* __restrict__ out) {
  const int idx = blockIdx.x;
  const int s = (idx & 1) * 256 + threadIdx.x;
  const int c = (idx >> 1) % OUT_;
  const int b = idx / (2 * OUT_);
  const long hbase = ((long)b * S_ + s) * H_;
  const float* wr = linw + (long)c * H_;
  float acc = 0.f;
  if (h_mode == 0) {
    const float* hr = (const float*)h + hbase;
    float a0 = 0.f, a1 = 0.f, a2 = 0.f, a3 = 0.f;
#pragma unroll 9
    for (int k4 = 0; k4 < 45; ++k4) {
      const float4 hv = *(const float4*)(hr + k4 * 4);
      const float4 wv = *(const float4*)(wr + k4 * 4);
      a0 += hv.x * wv.x; a1 += hv.y * wv.y; a2 += hv.z * wv.z; a3 += hv.w * wv.w;
    }
    acc = ((a0 + a1) + (a2 + a3));
  } else {
    const __hip_bfloat16* hr = (const __hip_bfloat16*)h + hbase;
#pragma unroll 4
    for (int k = 0; k < H_; ++k) acc += toF(hr[k]) * wr[k];
  }
  out[((long)b * OUT_ + c) * S_ + s] = linb[c] + acc;
}

// ---------------------------------------------------------------------------
// mel block
// ---------------------------------------------------------------------------
__global__ __launch_bounds__(256) void mel_kernel(
    const float* __restrict__ in, float* __restrict__ out,
    const void* __restrict__ mw, const void* __restrict__ mb,
    int l, const int* __restrict__ flag) {
  const int fl = *flag;
  const int idx = blockIdx.x;
  const int s = (idx & 1) * 256 + threadIdx.x;
  const int c = (idx >> 1) % OUT_;
  const int b = idx / (2 * OUT_);
  const int j = c % 3, i = c / 3;
  float acc = ldr(mb, (l * 3 + j) * 20 + i, fl);
  const long wbase = (long)((l * 3 + j) * 20 + i) * 15;
#pragma unroll
  for (int q = 0; q < 3; ++q) {
    const int ch = 3 * i + q + j - 1;
    if (ch < 0 || ch >= OUT_) continue;
    const float* xr = in + ((long)b * OUT_ + ch) * S_;
#pragma unroll
    for (int k = 0; k < 5; ++k) {
      const int sp = s + k - 2;
      if (sp < 0 || sp >= S_) continue;
      acc += ldr(mw, wbase + q * 5 + k, fl) * xr[sp];
    }
  }
  out[((long)b * OUT_ + c) * S_ + s] = acc + in[((long)b * OUT_ + c) * S_ + s];
}

// ---------------------------------------------------------------------------
// residual grouped conv + transpose to [B][S][60]; store dtype per flag
// ---------------------------------------------------------------------------
__global__ __launch_bounds__(256) void res_kernel(
    const float* __restrict__ lin, const float* __restrict__ mel,
    const void* __restrict__ rw, const void* __restrict__ rb,
    void* __restrict__ outp, const int* __restrict__ flag) {
  const int fl = *flag;
  const int q = threadIdx.x >> 6, lane = threadIdx.x & 63;
  const int bs = blockIdx.x * 4 + q;
  const int b = bs / S_, s = bs % S_;
  if (lane >= OUT_) return;
  const int c = lane;
  float acc = ldr(rb, c, fl);
  const float* x0 = lin + ((long)b * OUT_ + c) * S_;
  const float* x1 = mel + ((long)b * OUT_ + c) * S_;
#pragma unroll
  for (int k = 0; k < 5; ++k) {
    const int sp = s + k - 2;
    if (sp < 0 || sp >= S_) continue;
    acc += ldr(rw, c * 10 + k, fl) * x0[sp] + ldr(rw, c * 10 + 5 + k, fl) * x1[sp];
  }
  const long oi = (long)bs * OUT_ + c;
  if (fl == 0) ((__hip_bfloat16*)outp)[oi] = __float2bfloat16(acc);
  else ((float*)outp)[oi] = acc;
}

// ---------------------------------------------------------------------------
extern "C" void kernel_launch(void* const* d_in, const int* in_sizes, int n_in,
                              void* d_out, int out_size, void* d_ws, size_t ws_size,
                              hipStream_t stream) {
  const void* x    = d_in[0];
  const void* wih0 = d_in[1];
  const void* wihr = d_in[2];
  const void* whh  = d_in[3];
  const void* bih  = d_in[4];
  const void* bhh  = d_in[5];
  const void* linw = d_in[6];
  const void* linb = d_in[7];
  const void* melw = d_in[8];
  const void* melb = d_in[9];
  const void* resw = d_in[10];
  const void* resb = d_in[11];

  float* ws = (float*)d_ws;
  const bool big = ws_size >= 40000000ull;

  unsigned FLAG_O, WF_O, XG0_O, XG1_O, H0_O, H1_O, STH_O, STC_O, LIN_O, M1_O, M2_O;
  int h_mode;
  if (big) {  // Mode A: TC=64 double-buffered xg, h fp32 (39.98 MB)
    h_mode = 0;
    XG0_O = 0u; XG1_O = 1474560u;              // 2 x [2048][720]
    H0_O = 2949120u; H1_O = 5898240u; WF_O = 8847360u;
    STH_O = 9984300u; STC_O = 9990060u; FLAG_O = 9995820u;
    LIN_O = 0u; M1_O = 983040u; M2_O = 1966080u;
  } else {    // Mode C: TC=32 single xg, h bf16 (19.34 MB), sequential
    h_mode = 1;
    FLAG_O = 0u; WF_O = 16u; XG0_O = 1136956u; XG1_O = 1136956u;
    H0_O = 1874236u; H1_O = 3348796u;
    STH_O = 4823356u; STC_O = 4829116u;
    LIN_O = 10876u; M1_O = 993916u; M2_O = 1976956u;
  }
  int* flag = (int*)(ws + FLAG_O);
  float* wf  = ws + WF_O;
  float* sth = ws + STH_O;
  float* stc = ws + STC_O;
  float* lin = ws + LIN_O;
  float* m1  = ws + M1_O;
  float* m2  = ws + M2_O;
  float* xgb[2] = {ws + XG0_O, ws + XG1_O};
  void* hbufs[2] = {(void*)(ws + H0_O), (void*)(ws + H1_O)};
  const unsigned* wpk = (const unsigned*)(wf + WFO_WHH);

  detect_kernel<<<1, 256, 0, stream>>>((const unsigned short*)x, flag);
  prep_kernel<<<(WF_TOT + 255) / 256, 256, 0, stream>>>(
      wih0, wihr, whh, bih, bhh, linw, linb, wf, flag);

  const void* afinal;
  if (big) {
    // prologue: gemm-only for global chunk 0 (layer 0, t0=0)
    fused_kernel<<<160, 768, 0, stream>>>(
        xgb[0], wpk, hbufs[0], 0, sth, stc, 0, 64, /*nlstm=*/0,
        x, 0, flag, wf + WFO_WIH0, wf + WFO_BIAS, xgb[0], IN_, 0, 6, 384);
    for (int gc = 0; gc < 32; ++gc) {
      const int l = gc >> 3, ch = gc & 7;
      const int gcn = gc + 1;
      const int ln = gcn >> 3, chn = gcn & 7;
      const int ntiles = (gc == 31) ? 0 : 384;
      const void* ga; int ak; const float* gW; const float* gb2; float* xgn;
      int gK, gt0;
      if (gc == 31) {  // dead args for the gemm side
        ga = x; ak = 0; gW = wf + WFO_WIH0; gb2 = wf + WFO_BIAS;
        xgn = xgb[0]; gK = IN_; gt0 = 0;
      } else {
        ga = (ln == 0) ? x : (const void*)hbufs[(ln - 1) & 1];
        ak = (ln == 0) ? 0 : 1;
        gW = (ln == 0) ? (wf + WFO_WIH0)
                       : (wf + WFO_WIHR + (unsigned)(ln - 1) * G4_ * H_);
        gb2 = wf + WFO_BIAS + (unsigned)ln * G4_;
        xgn = xgb[gcn & 1]; gK = (ln == 0) ? IN_ : H_; gt0 = chn * 64;
      }
      fused_kernel<<<160, 768, 0, stream>>>(
          xgb[gc & 1], wpk + (unsigned)l * PKL_, hbufs[l & 1], 0,
          sth, stc, ch * 64, 64, 32,
          ga, ak, flag, gW, gb2, xgn, gK, gt0, 6, ntiles);
    }
    afinal = hbufs[1];  // layer 3
  } else {
    // sequential fallback: gemm-only then lstm-only per TC=32 chunk
    const void* aprev = nullptr;
    for (int l = 0; l < 4; ++l) {
      const unsigned* wpk_l = wpk + (unsigned)l * PKL_;
      const float* bias_l = wf + WFO_BIAS + (unsigned)l * G4_;
      const float* wih_l  = (l == 0) ? (wf + WFO_WIH0)
                                     : (wf + WFO_WIHR + (unsigned)(l - 1) * G4_ * H_);
      const void* a  = (l == 0) ? x : aprev;
      const int ak = (l == 0) ? 0 : 2;
      const int K = (l == 0) ? IN_ : H_;
      void* hcur = hbufs[l & 1];
      for (int ch = 0; ch < 16; ++ch) {
        fused_kernel<<<64, 768, 0, stream>>>(
            xgb[0], wpk_l, hcur, 1, sth, stc, 0, 32, 0,
            a, ak, flag, wih_l, bias_l, xgb[0], K, ch * 32, 5, 192);
        fused_kernel<<<32, 768, 0, stream>>>(
            xgb[0], wpk_l, hcur, 1, sth, stc, ch * 32, 32, 32,
            x, 0, flag, wf + WFO_WIH0, wf + WFO_BIAS, xgb[0], IN_, 0, 5, 0);
      }
      aprev = hcur;
    }
    afinal = hbufs[1];
  }

  linear_kernel<<<B_ * OUT_ * 2, 256, 0, stream>>>(
      afinal, h_mode, wf + WFO_LINW, wf + WFO_LINB, lin);

  mel_kernel<<<B_ * OUT_ * 2, 256, 0, stream>>>(lin, m1, melw, melb, 0, flag);
  mel_kernel<<<B_ * OUT_ * 2, 256, 0, stream>>>(m1, m2, melw, melb, 1, flag);
  mel_kernel<<<B_ * OUT_ * 2, 256, 0, stream>>>(m2, m1, melw, melb, 2, flag);

  res_kernel<<<R_ / 4, 256, 0, stream>>>(lin, m1, resw, resb, d_out, flag);
}

// Round 8
// 2651.952 us; speedup vs baseline: 7.4891x; 1.4479x over previous
//
#include <hip/hip_runtime.h>
#include <hip/hip_bf16.h>

#define B_ 32
#define S_ 512
#define IN_ 300
#define H_ 180
#define G4_ 720
#define OUT_ 60
#define R_ 16384   // B_*S_
#define NPK_ 92    // f16-pair regs per thread (90 data + 2 zero pad)

// Unified fp32 weight-region sub-offsets (floats from wf base):
//   [linw 10800][linb 60][wih0 216000][wihr 388800][whh-region 518400][bias 2880]
//   whh-region holds PACKED f16-pair whh^T: [l][jp][o] uints (jp<92, o<720).
#define WFO_LINW 0u
#define WFO_LINB 10800u
#define WFO_WIH0 10860u
#define WFO_WIHR 226860u
#define WFO_WHH  615660u
#define WFO_BIAS 1134060u
#define WF_TOT   1136940u
#define PKL_ (NPK_ * G4_)   // 66,240 uints per layer

#if defined(__has_builtin)
#if __has_builtin(__builtin_amdgcn_fdot2)
#define HAVE_FDOT2 1
#endif
#endif

typedef _Float16 f16x2 __attribute__((ext_vector_type(2)));

__device__ __forceinline__ float sigf(float x)   { return 1.f / (1.f + __expf(-x)); }
__device__ __forceinline__ float tanhf2(float x) { return 2.f / (1.f + __expf(-2.f * x)) - 1.f; }
__device__ __forceinline__ float toF(__hip_bfloat16 x) { return __bfloat162float(x); }
__device__ __forceinline__ float ldr(const void* p, long i, int fl) {
  return fl ? ((const float*)p)[i] : toF(((const __hip_bfloat16*)p)[i]);
}
__device__ __forceinline__ unsigned f16b(_Float16 h) {
  union { _Float16 f; unsigned short s; } x; x.f = h; return x.s;
}
__device__ __forceinline__ float h2f(unsigned s) {
  union { unsigned short s; _Float16 f; } x; x.s = (unsigned short)(s & 0xFFFFu);
  return (float)x.f;
}
__device__ __forceinline__ f16x2 u2h(unsigned u) {
  union { unsigned u; f16x2 v; } x; x.u = u; return x.v;
}
__device__ __forceinline__ float fd2(unsigned hu, unsigned wu, float acc) {
#ifdef HAVE_FDOT2
  return __builtin_amdgcn_fdot2(u2h(hu), u2h(wu), acc, false);
#else
  return acc + h2f(hu) * h2f(wu) + h2f(hu >> 16) * h2f(wu >> 16);
#endif
}

// 23 groups x 4 packed weight words = 92 named scalars (no array -> SROA-proof)
#define REP23(M) M(0) M(1) M(2) M(3) M(4) M(5) M(6) M(7) M(8) M(9) M(10) \
  M(11) M(12) M(13) M(14) M(15) M(16) M(17) M(18) M(19) M(20) M(21) M(22)
#define LW(n) \
  unsigned w##n##a = wp0[(4*n+0)*G4_], w##n##b = wp0[(4*n+1)*G4_], \
           w##n##c = wp0[(4*n+2)*G4_], w##n##d = wp0[(4*n+3)*G4_];
#define PW(n) \
  asm volatile("" : "+v"(w##n##a), "+v"(w##n##b), "+v"(w##n##c), "+v"(w##n##d));
#define ST(n) { \
  const uint4 hh = *(const uint4*)&hpk[4*n]; \
  a0 = fd2(hh.x, w##n##a, a0); a1 = fd2(hh.y, w##n##b, a1); \
  a2 = fd2(hh.z, w##n##c, a2); a3 = fd2(hh.w, w##n##d, a3); }

// ---------------------------------------------------------------------------
// detect: bf16 vs fp32 raw inputs via exponent stats of x's first 2048 words
// ---------------------------------------------------------------------------
__global__ __launch_bounds__(256) void detect_kernel(
    const unsigned short* __restrict__ xw, int* __restrict__ flag) {
  __shared__ int cnt;
  if (threadIdx.x == 0) cnt = 0;
  __syncthreads();
  int lc = 0;
  for (int i = threadIdx.x; i < 2048; i += 256) {
    const int e = (xw[i] >> 7) & 0xFF;
    if (e >= 0xC0 || (e > 0 && e < 0x40)) lc++;
  }
  atomicAdd(&cnt, lc);
  __syncthreads();
  if (threadIdx.x == 0) *flag = (cnt > 100) ? 1 : 0;
}

// ---------------------------------------------------------------------------
// prep: raw weights -> ws. whh packed as f16 pairs transposed [l][jp][o]
// (pair jp = k's 2jp,2jp+1; jp>=90 zero). Others fp32. bias = bih+bhh.
// ---------------------------------------------------------------------------
__global__ __launch_bounds__(256) void prep_kernel(
    const void* __restrict__ wih0, const void* __restrict__ wihr,
    const void* __restrict__ whh,  const void* __restrict__ bih,
    const void* __restrict__ bhh,  const void* __restrict__ linw,
    const void* __restrict__ linb, float* __restrict__ wf,
    const int* __restrict__ flag) {
  const unsigned i = blockIdx.x * 256u + threadIdx.x;
  if (i >= WF_TOT) return;
  const int fl = *flag;
  if (i >= WFO_WHH && i < WFO_BIAS) {
    const unsigned j = i - WFO_WHH;
    unsigned u = 0u;
    if (j < 4u * PKL_) {
      const unsigned l = j / PKL_, r = j - l * PKL_;
      const unsigned jp = r / G4_, o = r - jp * G4_;
      if (jp < 90u) {
        const long base = (long)l * 129600 + (long)o * H_;
        const _Float16 w0 = (_Float16)ldr(whh, base + 2 * jp, fl);
        const _Float16 w1 = (_Float16)ldr(whh, base + 2 * jp + 1, fl);
        u = f16b(w0) | (f16b(w1) << 16);
      }
    }
    ((unsigned*)wf)[i] = u;
    return;
  }
  float v;
  if (i < WFO_LINB)            v = ldr(linw, i, fl);
  else if (i < WFO_WIH0)       v = ldr(linb, i - WFO_LINB, fl);
  else if (i < WFO_WIHR)       v = ldr(wih0, i - WFO_WIH0, fl);
  else if (i < WFO_WHH)        v = ldr(wihr, i - WFO_WIHR, fl);
  else { const unsigned j = i - WFO_BIAS; v = ldr(bih, j, fl) + ldr(bhh, j, fl); }
  wf[i] = v;
}

// ---------------------------------------------------------------------------
// fused_kernel: blocks [0,nlstm) run the LSTM recurrence for the CURRENT
// chunk; remaining blocks compute the NEXT chunk's input projection.
//   lstm: Whh resident as 92 pinned packed f16 pairs. h kept as SINGLE f16
//   in LDS (23 broadcast b128 reads/step instead of 46) — the LDS issue
//   pipe is the measured bottleneck (R6: 552 issues x 8 cyc = measured step).
// ---------------------------------------------------------------------------
__global__ __launch_bounds__(768, 3) void fused_kernel(
    // lstm part
    const float* __restrict__ xg, const unsigned* __restrict__ wpk,
    void* __restrict__ hout, int h_mode,
    float* __restrict__ st_h, float* __restrict__ st_c,
    int t0, int TC, int nlstm,
    // gemm part
    const void* __restrict__ ga, int a_kind, const int* __restrict__ flag,
    const float* __restrict__ gW, const float* __restrict__ gbias,
    float* __restrict__ xgn, int gK, int gt0, int tcbits, int ntiles) {
  __shared__ __align__(16) unsigned hpk[NPK_];   // single-f16 packed h
  __shared__ float gbuf[G4_];
  __shared__ __align__(16) float Ast[3][20][68];
  __shared__ __align__(16) float Bst[3][20][68];

  const int bid = blockIdx.x;
  if (bid < nlstm) {
    // ---------------- LSTM body ----------------
    const int b = bid;
    const int o = threadIdx.x;
    const bool act = o < G4_;
    const int oc = act ? o : 0;
    const unsigned* wp0 = wpk + oc;
    REP23(LW)                 // 92 coalesced one-time loads
    REP23(PW)                 // pin each named scalar
    float c = 0.f;
    if (o == 180 || o == 181) hpk[o - 90] = 0u;
    if (o < H_) {
      float h = 0.f;
      if (t0 != 0) { h = st_h[b * H_ + o]; c = st_c[b * H_ + o]; }
      const unsigned v = f16b((_Float16)h);
      const unsigned nx = __shfl_down(v, 1);
      if ((o & 1) == 0) hpk[o >> 1] = v | (nx << 16);
    }
    const float* xgp = xg + (long)b * TC * G4_ + oc;
    float xcur = xgp[0];
    __syncthreads();
    for (int tl = 0; tl < TC; ++tl) {
      {
        float a0 = xcur, a1 = 0.f, a2 = 0.f, a3 = 0.f;
        REP23(ST)
        const float acc = (a0 + a1) + (a2 + a3);
        const bool isg = (o >= 2 * H_) && (o < 3 * H_);
        if (act) gbuf[o] = isg ? tanhf2(acc) : sigf(acc);
        const int tn = (tl + 1 < TC) ? tl + 1 : tl;   // prefetch next xg
        xcur = xgp[(long)tn * G4_];
      }
      __syncthreads();
      if (o < H_) {
        c = gbuf[H_ + o] * c + gbuf[o] * gbuf[2 * H_ + o];
        const float h = gbuf[3 * H_ + o] * tanhf2(c);
        const long gi = ((long)b * S_ + t0 + tl) * H_ + o;
        if (h_mode == 0) ((float*)hout)[gi] = h;
        else ((__hip_bfloat16*)hout)[gi] = __float2bfloat16(h);
        const unsigned v = f16b((_Float16)h);
        const unsigned nx = __shfl_down(v, 1);
        if ((o & 1) == 0) hpk[o >> 1] = v | (nx << 16);
        if (tl == TC - 1) { st_h[b * H_ + o] = h; st_c[b * H_ + o] = c; }
      }
      __syncthreads();
    }
    return;
  }

  // ---------------- GEMM body (next chunk's xg) ----------------
  if ((bid - nlstm) * 3 >= ntiles) return;  // block-uniform (ntiles % 3 == 0)
  const int g = threadIdx.x >> 8, t = threadIdx.x & 255;
  const int ti = (bid - nlstm) * 3 + g;
  const int nrt = (B_ * TC) >> 6;           // row tiles in the chunk
  const int rt = ti % nrt, ct = ti / nrt;
  const int rho0 = rt << 6, o0 = ct << 6;
  const int tx = t & 15, ty = t >> 4;
  const int fl = *flag;
  const int tcm = (1 << tcbits) - 1;
  float acc[4][4] = {};
  for (int k0 = 0; k0 < gK; k0 += 20) {
    for (int e = t; e < 1280; e += 256) {
      const int rl = e / 20, kk = e % 20;
      const int rho = rho0 + rl;
      const int bb = rho >> tcbits, tl = rho & tcm;
      const long gi = ((long)bb * S_ + gt0 + tl) * gK + k0 + kk;
      float av;
      if (a_kind == 1)      av = ((const float*)ga)[gi];
      else if (a_kind == 2) av = toF(((const __hip_bfloat16*)ga)[gi]);
      else                  av = ldr(ga, gi, fl);
      Ast[g][kk][rl] = av;
      const int o = o0 + rl;
      Bst[g][kk][rl] = (o < G4_) ? gW[(long)o * gK + k0 + kk] : 0.f;
    }
    __syncthreads();
#pragma unroll
    for (int kk = 0; kk < 20; ++kk) {
      const float4 a4 = *(const float4*)&Ast[g][kk][ty * 4];
      const float4 b4 = *(const float4*)&Bst[g][kk][tx * 4];
      const float av[4] = {a4.x, a4.y, a4.z, a4.w};
      const float bv[4] = {b4.x, b4.y, b4.z, b4.w};
#pragma unroll
      for (int i = 0; i < 4; ++i)
#pragma unroll
        for (int j = 0; j < 4; ++j) acc[i][j] += av[i] * bv[j];
    }
    __syncthreads();
  }
#pragma unroll
  for (int i = 0; i < 4; ++i) {
    const int rho = rho0 + ty * 4 + i;
#pragma unroll
    for (int j = 0; j < 4; ++j) {
      const int o = o0 + tx * 4 + j;
      if (o < G4_) xgn[(long)rho * G4_ + o] = acc[i][j] + gbias[o];
    }
  }
}

// ---------------------------------------------------------------------------
// linear: lin[b][c][s] = h[(b,s)] . linW[c] + linb[c]
// ---------------------------------------------------------------------------
__global__ __launch_bounds__(256) void linear_kernel(
    const void* __restrict__ h, int h_mode, const float* __restrict__ linw,
    const float* __restrict__ linb, float* __restrict__ out) {
  const int idx = blockIdx.x;
  const int s = (idx & 1) * 256 + threadIdx.x;
  const int c = (idx >> 1) % OUT_;
  const int b = idx / (2 * OUT_);
  const long hbase = ((long)b * S_ + s) * H_;
  const float* wr = linw + (long)c * H_;
  float acc = 0.f;
  if (h_mode == 0) {
    const float* hr = (const float*)h + hbase;
    float a0 = 0.f, a1 = 0.f, a2 = 0.f, a3 = 0.f;
#pragma unroll 9
    for (int k4 = 0; k4 < 45; ++k4) {
      const float4 hv = *(const float4*)(hr + k4 * 4);
      const float4 wv = *(const float4*)(wr + k4 * 4);
      a0 += hv.x * wv.x; a1 += hv.y * wv.y; a2 += hv.z * wv.z; a3 += hv.w * wv.w;
    }
    acc = ((a0 + a1) + (a2 + a3));
  } else {
    const __hip_bfloat16* hr = (const __hip_bfloat16*)h + hbase;
#pragma unroll 4
    for (int k = 0; k < H_; ++k) acc += toF(hr[k]) * wr[k];
  }
  out[((long)b * OUT_ + c) * S_ + s] = linb[c] + acc;
}

// ---------------------------------------------------------------------------
// mel block
// ---------------------------------------------------------------------------
__global__ __launch_bounds__(256) void mel_kernel(
    const float* __restrict__ in, float* __restrict__ out,
    const void* __restrict__ mw, const void* __restrict__ mb,
    int l, const int* __restrict__ flag) {
  const int fl = *flag;
  const int idx = blockIdx.x;
  const int s = (idx & 1) * 256 + threadIdx.x;
  const int c = (idx >> 1) % OUT_;
  const int b = idx / (2 * OUT_);
  const int j = c % 3, i = c / 3;
  float acc = ldr(mb, (l * 3 + j) * 20 + i, fl);
  const long wbase = (long)((l * 3 + j) * 20 + i) * 15;
#pragma unroll
  for (int q = 0; q < 3; ++q) {
    const int ch = 3 * i + q + j - 1;
    if (ch < 0 || ch >= OUT_) continue;
    const float* xr = in + ((long)b * OUT_ + ch) * S_;
#pragma unroll
    for (int k = 0; k < 5; ++k) {
      const int sp = s + k - 2;
      if (sp < 0 || sp >= S_) continue;
      acc += ldr(mw, wbase + q * 5 + k, fl) * xr[sp];
    }
  }
  out[((long)b * OUT_ + c) * S_ + s] = acc + in[((long)b * OUT_ + c) * S_ + s];
}

// ---------------------------------------------------------------------------
// residual grouped conv + transpose to [B][S][60]; store dtype per flag
// ---------------------------------------------------------------------------
__global__ __launch_bounds__(256) void res_kernel(
    const float* __restrict__ lin, const float* __restrict__ mel,
    const void* __restrict__ rw, const void* __restrict__ rb,
    void* __restrict__ outp, const int* __restrict__ flag) {
  const int fl = *flag;
  const int q = threadIdx.x >> 6, lane = threadIdx.x & 63;
  const int bs = blockIdx.x * 4 + q;
  const int b = bs / S_, s = bs % S_;
  if (lane >= OUT_) return;
  const int c = lane;
  float acc = ldr(rb, c, fl);
  const float* x0 = lin + ((long)b * OUT_ + c) * S_;
  const float* x1 = mel + ((long)b * OUT_ + c) * S_;
#pragma unroll
  for (int k = 0; k < 5; ++k) {
    const int sp = s + k - 2;
    if (sp < 0 || sp >= S_) continue;
    acc += ldr(rw, c * 10 + k, fl) * x0[sp] + ldr(rw, c * 10 + 5 + k, fl) * x1[sp];
  }
  const long oi = (long)bs * OUT_ + c;
  if (fl == 0) ((__hip_bfloat16*)outp)[oi] = __float2bfloat16(acc);
  else ((float*)outp)[oi] = acc;
}

// ---------------------------------------------------------------------------
extern "C" void kernel_launch(void* const* d_in, const int* in_sizes, int n_in,
                              void* d_out, int out_size, void* d_ws, size_t ws_size,
                              hipStream_t stream) {
  const void* x    = d_in[0];
  const void* wih0 = d_in[1];
  const void* wihr = d_in[2];
  const void* whh  = d_in[3];
  const void* bih  = d_in[4];
  const void* bhh  = d_in[5];
  const void* linw = d_in[6];
  const void* linb = d_in[7];
  const void* melw = d_in[8];
  const void* melb = d_in[9];
  const void* resw = d_in[10];
  const void* resb = d_in[11];

  float* ws = (float*)d_ws;
  const bool big = ws_size >= 40000000ull;

  unsigned FLAG_O, WF_O, XG0_O, XG1_O, H0_O, H1_O, STH_O, STC_O, LIN_O, M1_O, M2_O;
  int h_mode;
  if (big) {  // Mode A: TC=64 double-buffered xg, h fp32 (39.98 MB)
    h_mode = 0;
    XG0_O = 0u; XG1_O = 1474560u;              // 2 x [2048][720]
    H0_O = 2949120u; H1_O = 5898240u; WF_O = 8847360u;
    STH_O = 9984300u; STC_O = 9990060u; FLAG_O = 9995820u;
    LIN_O = 0u; M1_O = 983040u; M2_O = 1966080u;
  } else {    // Mode C: TC=32 single xg, h bf16 (19.34 MB), sequential
    h_mode = 1;
    FLAG_O = 0u; WF_O = 16u; XG0_O = 1136956u; XG1_O = 1136956u;
    H0_O = 1874236u; H1_O = 3348796u;
    STH_O = 4823356u; STC_O = 4829116u;
    LIN_O = 10876u; M1_O = 993916u; M2_O = 1976956u;
  }
  int* flag = (int*)(ws + FLAG_O);
  float* wf  = ws + WF_O;
  float* sth = ws + STH_O;
  float* stc = ws + STC_O;
  float* lin = ws + LIN_O;
  float* m1  = ws + M1_O;
  float* m2  = ws + M2_O;
  float* xgb[2] = {ws + XG0_O, ws + XG1_O};
  void* hbufs[2] = {(void*)(ws + H0_O), (void*)(ws + H1_O)};
  const unsigned* wpk = (const unsigned*)(wf + WFO_WHH);

  detect_kernel<<<1, 256, 0, stream>>>((const unsigned short*)x, flag);
  prep_kernel<<<(WF_TOT + 255) / 256, 256, 0, stream>>>(
      wih0, wihr, whh, bih, bhh, linw, linb, wf, flag);

  const void* afinal;
  if (big) {
    // prologue: gemm-only for global chunk 0 (layer 0, t0=0)
    fused_kernel<<<160, 768, 0, stream>>>(
        xgb[0], wpk, hbufs[0], 0, sth, stc, 0, 64, /*nlstm=*/0,
        x, 0, flag, wf + WFO_WIH0, wf + WFO_BIAS, xgb[0], IN_, 0, 6, 384);
    for (int gc = 0; gc < 32; ++gc) {
      const int l = gc >> 3, ch = gc & 7;
      const int gcn = gc + 1;
      const int ln = gcn >> 3, chn = gcn & 7;
      const int ntiles = (gc == 31) ? 0 : 384;
      const void* ga; int ak; const float* gW; const float* gb2; float* xgn;
      int gK, gt0;
      if (gc == 31) {  // dead args for the gemm side
        ga = x; ak = 0; gW = wf + WFO_WIH0; gb2 = wf + WFO_BIAS;
        xgn = xgb[0]; gK = IN_; gt0 = 0;
      } else {
        ga = (ln == 0) ? x : (const void*)hbufs[(ln - 1) & 1];
        ak = (ln == 0) ? 0 : 1;
        gW = (ln == 0) ? (wf + WFO_WIH0)
                       : (wf + WFO_WIHR + (unsigned)(ln - 1) * G4_ * H_);
        gb2 = wf + WFO_BIAS + (unsigned)ln * G4_;
        xgn = xgb[gcn & 1]; gK = (ln == 0) ? IN_ : H_; gt0 = chn * 64;
      }
      fused_kernel<<<160, 768, 0, stream>>>(
          xgb[gc & 1], wpk + (unsigned)l * PKL_, hbufs[l & 1], 0,
          sth, stc, ch * 64, 64, 32,
          ga, ak, flag, gW, gb2, xgn, gK, gt0, 6, ntiles);
    }
    afinal = hbufs[1];  // layer 3
  } else {
    // sequential fallback: gemm-only then lstm-only per TC=32 chunk
    const void* aprev = nullptr;
    for (int l = 0; l < 4; ++l) {
      const unsigned* wpk_l = wpk + (unsigned)l * PKL_;
      const float* bias_l = wf + WFO_BIAS + (unsigned)l * G4_;
      const float* wih_l  = (l == 0) ? (wf + WFO_WIH0)
                                     : (wf + WFO_WIHR + (unsigned)(l - 1) * G4_ * H_);
      const void* a  = (l == 0) ? x : aprev;
      const int ak = (l == 0) ? 0 : 2;
      const int K = (l == 0) ? IN_ : H_;
      void* hcur = hbufs[l & 1];
      for (int ch = 0; ch < 16; ++ch) {
        fused_kernel<<<64, 768, 0, stream>>>(
            xgb[0], wpk_l, hcur, 1, sth, stc, 0, 32, 0,
            a, ak, flag, wih_l, bias_l, xgb[0], K, ch * 32, 5, 192);
        fused_kernel<<<32, 768, 0, stream>>>(
            xgb[0], wpk_l, hcur, 1, sth, stc, ch * 32, 32, 32,
            x, 0, flag, wf + WFO_WIH0, wf + WFO_BIAS, xgb[0], IN_, 0, 5, 0);
      }
      aprev = hcur;
    }
    afinal = hbufs[1];
  }

  linear_kernel<<<B_ * OUT_ * 2, 256, 0, stream>>>(
      afinal, h_mode, wf + WFO_LINW, wf + WFO_LINB, lin);

  mel_kernel<<<B_ * OUT_ * 2, 256, 0, stream>>>(lin, m1, melw, melb, 0, flag);
  mel_kernel<<<B_ * OUT_ * 2, 256, 0, stream>>>(m1, m2, melw, melb, 1, flag);
  mel_kernel<<<B_ * OUT_ * 2, 256, 0, stream>>>(m2, m1, melw, melb, 2, flag);

  res_kernel<<<R_ / 4, 256, 0, stream>>>(lin, m1, resw, resb, d_out, flag);
}

// Round 11
// 2009.284 us; speedup vs baseline: 9.8845x; 1.3198x over previous
//
#include <hip/hip_runtime.h>
#include <hip/hip_bf16.h>

#define B_ 32
#define S_ 512
#define IN_ 300
#define H_ 180
#define G4_ 720
#define OUT_ 60
#define R_ 16384
#define TC_ 32
#define NC_ 16
#define NPK_ 92

// packed-weight region word offsets (wfu = uint/float view of same region)
#define PWHH_O  0u        // uints [4][92][720] f16-pair Whh^T = 264,960
#define W0F_O   264960u   // fp32 [720][300] Wih0 = 216,000
#define WRF_O   480960u   // fp32 [3][720][180] WihR = 388,800
#define BIASF_O 869760u   // fp32 [4][720] (bih+bhh)
#define LINWF_O 872640u   // fp32 [60][180]
#define LINBF_O 883440u   // fp32 [60]
#define WFT_    883500u

// ws float offsets (total 9,408,301 fl = 37.6 MB; ws >= 40 MB measured)
// R9 BUG FIX: h3 is [16384][180] bf16 = 1,474,560 FLOATS (was 737,280 —
// layer-3 writes for b>=16 overflowed into the weight region).
#define XG_O   0u         // [4 layers][2 ring][1024][720] fp32 = 5,898,240
#define HR_O   5898240u   // [3 layers][2 ring][1024][180] fp32 = 1,105,920
#define H3_O   7004160u   // bf16 [16384][180] = 1,474,560 fl
#define WFU_O  8478720u   // 883,500 fl
#define STH_O  9362220u   // [4][32][180]
#define STC_O  9385260u
#define FLAG_O 9408300u
#define XGSLOT 737280
#define HRSLOT 184320

#if defined(__has_builtin)
#if __has_builtin(__builtin_amdgcn_fdot2)
#define HAVE_FDOT2 1
#endif
#endif

typedef _Float16 f16x2 __attribute__((ext_vector_type(2)));

struct Plan {
  int nl; int ll[4]; int lc[4];
  int ng; int gl[4]; int gc[4];
};

__device__ __forceinline__ float sigf(float x)   { return 1.f / (1.f + __expf(-x)); }
__device__ __forceinline__ float tanhf2(float x) { return 2.f / (1.f + __expf(-2.f * x)) - 1.f; }
__device__ __forceinline__ float toF(__hip_bfloat16 x) { return __bfloat162float(x); }
__device__ __forceinline__ float ldr(const void* p, long i, int fl) {
  return fl ? ((const float*)p)[i] : toF(((const __hip_bfloat16*)p)[i]);
}
__device__ __forceinline__ unsigned f16b(_Float16 h) {
  union { _Float16 f; unsigned short s; } x; x.f = h; return x.s;
}
__device__ __forceinline__ float h2f(unsigned s) {
  union { unsigned short s; _Float16 f; } x; x.s = (unsigned short)(s & 0xFFFFu);
  return (float)x.f;
}
__device__ __forceinline__ f16x2 u2h(unsigned u) {
  union { unsigned u; f16x2 v; } x; x.u = u; return x.v;
}
__device__ __forceinline__ float fd2(unsigned hu, unsigned wu, float acc) {
#ifdef HAVE_FDOT2
  return __builtin_amdgcn_fdot2(u2h(hu), u2h(wu), acc, false);
#else
  return acc + h2f(hu) * h2f(wu) + h2f(hu >> 16) * h2f(wu >> 16);
#endif
}
__device__ __forceinline__ unsigned packpair_f32(float lo, float hi) {
  return f16b((_Float16)lo) | (f16b((_Float16)hi) << 16);
}

// 23 groups x 4 Whh pair-words = 92 named scalars (SROA-proof, asm-pinned)
#define REP23(M) M(0) M(1) M(2) M(3) M(4) M(5) M(6) M(7) M(8) M(9) M(10) \
  M(11) M(12) M(13) M(14) M(15) M(16) M(17) M(18) M(19) M(20) M(21) M(22)
#define LW(n) \
  unsigned w##n##a = wp0[(4*n+0)*G4_], w##n##b = wp0[(4*n+1)*G4_], \
           w##n##c = wp0[(4*n+2)*G4_], w##n##d = wp0[(4*n+3)*G4_];
#define PW(n) \
  asm volatile("" : "+v"(w##n##a), "+v"(w##n##b), "+v"(w##n##c), "+v"(w##n##d));
#define ST(n) { \
  const uint4 hh = *(const uint4*)&hpk[4*n]; \
  a0 = fd2(hh.x, w##n##a, a0); a1 = fd2(hh.y, w##n##b, a1); \
  a2 = fd2(hh.z, w##n##c, a2); a3 = fd2(hh.w, w##n##d, a3); }

// ---------------------------------------------------------------------------
__global__ __launch_bounds__(256) void detect_kernel(
    const unsigned short* __restrict__ xw, int* __restrict__ flag) {
  __shared__ int cnt;
  if (threadIdx.x == 0) cnt = 0;
  __syncthreads();
  int lc = 0;
  for (int i = threadIdx.x; i < 2048; i += 256) {
    const int e = (xw[i] >> 7) & 0xFF;
    if (e >= 0xC0 || (e > 0 && e < 0x40)) lc++;
  }
  atomicAdd(&cnt, lc);
  __syncthreads();
  if (threadIdx.x == 0) *flag = (cnt > 100) ? 1 : 0;
}

// ---------------------------------------------------------------------------
// prep: Whh -> f16-pair packed transposed [l][jp][o]; rest fp32.
// ---------------------------------------------------------------------------
__global__ __launch_bounds__(256) void prep_kernel(
    const void* __restrict__ wih0, const void* __restrict__ wihr,
    const void* __restrict__ whh,  const void* __restrict__ bih,
    const void* __restrict__ bhh,  const void* __restrict__ linw,
    const void* __restrict__ linb, float* __restrict__ wf,
    const int* __restrict__ flag) {
  const unsigned i = blockIdx.x * 256u + threadIdx.x;
  if (i >= WFT_) return;
  const int fl = *flag;
  if (i < W0F_O) {            // Whh packed
    const unsigned l = i / 66240u, r = i % 66240u;
    const unsigned jp = r / 720u, o = r % 720u;
    unsigned u = 0u;
    if (jp < 90u) {
      const long b = (long)l * 129600 + (long)o * H_;
      u = packpair_f32(ldr(whh, b + 2 * jp, fl), ldr(whh, b + 2 * jp + 1, fl));
    }
    ((unsigned*)wf)[i] = u;
    return;
  }
  float v;
  if (i < WRF_O)        v = ldr(wih0, i - W0F_O, fl);
  else if (i < BIASF_O) v = ldr(wihr, i - WRF_O, fl);
  else if (i < LINWF_O) { const unsigned j = i - BIASF_O; v = ldr(bih, j, fl) + ldr(bhh, j, fl); }
  else if (i < LINBF_O) v = ldr(linw, i - LINWF_O, fl);
  else                  v = ldr(linb, i - LINBF_O, fl);
  wf[i] = v;
}

// ---------------------------------------------------------------------------
// fused: blocks [0, nl*32) = LSTM jobs; rest = barrier GEMM (3 tiles/block).
// ---------------------------------------------------------------------------
__global__ __launch_bounds__(768, 3) void fused_kernel(
    const void* __restrict__ x, const int* __restrict__ flag,
    const unsigned* __restrict__ wfu,
    float* __restrict__ xg, float* __restrict__ hr,
    __hip_bfloat16* __restrict__ h3,
    float* __restrict__ sth, float* __restrict__ stc, Plan p) {
  __shared__ __align__(16) unsigned hpk[NPK_];
  __shared__ float gbuf[G4_];
  __shared__ __align__(16) float Ast[3][20][68];
  __shared__ __align__(16) float Bst[3][20][68];

  const int bid = blockIdx.x;
  if (bid < p.nl * 32) {
    // ---------------- LSTM ----------------
    const int j = bid >> 5, b = bid & 31;
    const int l = p.ll[j], c = p.lc[j];
    const int o = threadIdx.x;
    const bool act = o < G4_;
    const int oc = act ? o : 0;
    const unsigned* wp0 = wfu + PWHH_O + (unsigned)l * (NPK_ * G4_) + oc;
    REP23(LW)
    REP23(PW)
    const float* xgs = xg + (long)(l * 2 + (c & 1)) * XGSLOT;
    float* hrs = hr + (long)((l < 3 ? l : 0) * 2 + (c & 1)) * HRSLOT;
    float cst = 0.f;
    if (o == 180 || o == 181) hpk[o - 90] = 0u;
    if (o < H_) {
      float h = 0.f;
      if (c != 0) { h = sth[(l * 32 + b) * H_ + o]; cst = stc[(l * 32 + b) * H_ + o]; }
      const unsigned v = f16b((_Float16)h);
      const unsigned nx = __shfl_down(v, 1);
      if ((o & 1) == 0) hpk[o >> 1] = v | (nx << 16);
    }
    const float* xgp = xgs + (long)b * TC_ * G4_ + oc;
    float xcur = xgp[0];
    __syncthreads();
    for (int tl = 0; tl < TC_; ++tl) {
      {
        float a0 = xcur, a1 = 0.f, a2 = 0.f, a3 = 0.f;
        REP23(ST)
        const float acc = (a0 + a1) + (a2 + a3);
        const bool isg = (o >= 2 * H_) && (o < 3 * H_);
        if (act) gbuf[o] = isg ? tanhf2(acc) : sigf(acc);
        const int tn = (tl + 1 < TC_) ? tl + 1 : tl;
        xcur = xgp[(long)tn * G4_];
      }
      __syncthreads();
      if (o < H_) {
        cst = gbuf[H_ + o] * cst + gbuf[o] * gbuf[2 * H_ + o];
        const float h = gbuf[3 * H_ + o] * tanhf2(cst);
        if (l < 3) hrs[(b * TC_ + tl) * H_ + o] = h;
        else h3[((long)b * S_ + c * TC_ + tl) * H_ + o] = __float2bfloat16(h);
        const unsigned v = f16b((_Float16)h);
        const unsigned nx = __shfl_down(v, 1);
        if ((o & 1) == 0) hpk[o >> 1] = v | (nx << 16);
        if (tl == TC_ - 1) {
          sth[(l * 32 + b) * H_ + o] = h; stc[(l * 32 + b) * H_ + o] = cst;
        }
      }
      __syncthreads();
    }
    return;
  }

  // ---------------- GEMM (R3-R7 proven structure) ----------------
  const int gb = bid - p.nl * 32;
  const int g = threadIdx.x >> 8, t = threadIdx.x & 255;
  const int ti = gb * 3 + g;
  const int jj = ti / 192, idx = ti % 192;
  const int rt = idx & 15, ct = idx >> 4;
  const int l = p.gl[jj], c = p.gc[jj];
  const int fl = *flag;
  const float* wff = (const float*)wfu;
  const int K = (l == 0) ? IN_ : H_;
  const float* W = (l == 0) ? (wff + W0F_O)
                            : (wff + WRF_O + (unsigned)(l - 1) * 129600u);
  const float* bias = wff + BIASF_O + (unsigned)l * G4_;
  const float* hA = (l == 0) ? nullptr
                  : hr + (long)((l - 1) * 2 + (c & 1)) * HRSLOT;
  float* dst = xg + (long)(l * 2 + (c & 1)) * XGSLOT;
  const int rho0 = rt * 64, o0 = ct * 64;
  const int tx = t & 15, ty = t >> 4;
  float acc[4][4] = {};
  for (int k0 = 0; k0 < K; k0 += 20) {
    for (int e = t; e < 1280; e += 256) {
      const int rl = e / 20, kk = e % 20;
      const int rho = rho0 + rl;
      float av;
      if (l == 0) {
        const int bb = rho >> 5, tl = rho & 31;
        av = ldr(x, ((long)bb * S_ + c * TC_ + tl) * IN_ + k0 + kk, fl);
      } else {
        av = hA[(long)rho * H_ + k0 + kk];
      }
      Ast[g][kk][rl] = av;
      const int o = o0 + rl;
      Bst[g][kk][rl] = (o < G4_) ? W[(long)o * K + k0 + kk] : 0.f;
    }
    __syncthreads();
#pragma unroll
    for (int kk = 0; kk < 20; ++kk) {
      const float4 a4 = *(const float4*)&Ast[g][kk][ty * 4];
      const float4 b4 = *(const float4*)&Bst[g][kk][tx * 4];
      const float av[4] = {a4.x, a4.y, a4.z, a4.w};
      const float bv[4] = {b4.x, b4.y, b4.z, b4.w};
#pragma unroll
      for (int i = 0; i < 4; ++i)
#pragma unroll
        for (int j2 = 0; j2 < 4; ++j2) acc[i][j2] += av[i] * bv[j2];
    }
    __syncthreads();
  }
#pragma unroll
  for (int i = 0; i < 4; ++i) {
    const int rho = rho0 + ty * 4 + i;
#pragma unroll
    for (int j2 = 0; j2 < 4; ++j2) {
      const int o = o0 + tx * 4 + j2;
      if (o < G4_) dst[(long)rho * G4_ + o] = acc[i][j2] + bias[o];
    }
  }
}

// ---------------------------------------------------------------------------
__global__ __launch_bounds__(256) void linear_kernel(
    const __hip_bfloat16* __restrict__ h, const float* __restrict__ linw,
    const float* __restrict__ linb, float* __restrict__ out) {
  const int idx = blockIdx.x;
  const int s = (idx & 1) * 256 + threadIdx.x;
  const int c = (idx >> 1) % OUT_;
  const int b = idx / (2 * OUT_);
  const __hip_bfloat16* hrow = h + ((long)b * S_ + s) * H_;
  const float* wr = linw + (long)c * H_;
  float acc = 0.f;
#pragma unroll 4
  for (int k = 0; k < H_; ++k) acc += toF(hrow[k]) * wr[k];
  out[((long)b * OUT_ + c) * S_ + s] = linb[c] + acc;
}

// ---------------------------------------------------------------------------
__global__ __launch_bounds__(256) void mel_kernel(
    const float* __restrict__ in, float* __restrict__ out,
    const void* __restrict__ mw, const void* __restrict__ mb,
    int l, const int* __restrict__ flag) {
  const int fl = *flag;
  const int idx = blockIdx.x;
  const int s = (idx & 1) * 256 + threadIdx.x;
  const int c = (idx >> 1) % OUT_;
  const int b = idx / (2 * OUT_);
  const int j = c % 3, i = c / 3;
  float acc = ldr(mb, (l * 3 + j) * 20 + i, fl);
  const long wbase = (long)((l * 3 + j) * 20 + i) * 15;
#pragma unroll
  for (int q = 0; q < 3; ++q) {
    const int ch = 3 * i + q + j - 1;
    if (ch < 0 || ch >= OUT_) continue;
    const float* xr = in + ((long)b * OUT_ + ch) * S_;
#pragma unroll
    for (int k = 0; k < 5; ++k) {
      const int sp = s + k - 2;
      if (sp < 0 || sp >= S_) continue;
      acc += ldr(mw, wbase + q * 5 + k, fl) * xr[sp];
    }
  }
  out[((long)b * OUT_ + c) * S_ + s] = acc + in[((long)b * OUT_ + c) * S_ + s];
}

// ---------------------------------------------------------------------------
__global__ __launch_bounds__(256) void res_kernel(
    const float* __restrict__ lin, const float* __restrict__ mel,
    const void* __restrict__ rw, const void* __restrict__ rb,
    void* __restrict__ outp, const int* __restrict__ flag) {
  const int fl = *flag;
  const int q = threadIdx.x >> 6, lane = threadIdx.x & 63;
  const int bs = blockIdx.x * 4 + q;
  const int b = bs / S_, s = bs % S_;
  if (lane >= OUT_) return;
  const int c = lane;
  float acc = ldr(rb, c, fl);
  const float* x0 = lin + ((long)b * OUT_ + c) * S_;
  const float* x1 = mel + ((long)b * OUT_ + c) * S_;
#pragma unroll
  for (int k = 0; k < 5; ++k) {
    const int sp = s + k - 2;
    if (sp < 0 || sp >= S_) continue;
    acc += ldr(rw, c * 10 + k, fl) * x0[sp] + ldr(rw, c * 10 + 5 + k, fl) * x1[sp];
  }
  const long oi = (long)bs * OUT_ + c;
  if (fl == 0) ((__hip_bfloat16*)outp)[oi] = __float2bfloat16(acc);
  else ((float*)outp)[oi] = acc;
}

// ---------------------------------------------------------------------------
extern "C" void kernel_launch(void* const* d_in, const int* in_sizes, int n_in,
                              void* d_out, int out_size, void* d_ws, size_t ws_size,
                              hipStream_t stream) {
  const void* x    = d_in[0];
  const void* wih0 = d_in[1];
  const void* wihr = d_in[2];
  const void* whh  = d_in[3];
  const void* bih  = d_in[4];
  const void* bhh  = d_in[5];
  const void* linw = d_in[6];
  const void* linb = d_in[7];
  const void* melw = d_in[8];
  const void* melb = d_in[9];
  const void* resw = d_in[10];
  const void* resb = d_in[11];

  float* ws = (float*)d_ws;
  float* xg = ws + XG_O;
  float* hrp = ws + HR_O;
  __hip_bfloat16* h3 = (__hip_bfloat16*)(ws + H3_O);
  float* wf = ws + WFU_O;
  const unsigned* wfu = (const unsigned*)wf;
  float* sth = ws + STH_O;
  float* stc = ws + STC_O;
  int* flag = (int*)(ws + FLAG_O);
  float* lin = ws + XG_O;            // epilogue aliases dead xg region
  float* m1 = lin + 983040;
  float* m2 = m1 + 983040;

  detect_kernel<<<1, 256, 0, stream>>>((const unsigned short*)x, flag);
  prep_kernel<<<(WFT_ + 255) / 256, 256, 0, stream>>>(
      wih0, wihr, whh, bih, bhh, linw, linb, wf, flag);

  // prologue: gemm(0,0) only
  {
    Plan p = {};
    p.nl = 0; p.ng = 1; p.gl[0] = 0; p.gc[0] = 0;
    fused_kernel<<<64, 768, 0, stream>>>(x, flag, wfu, xg, hrp, h3, sth, stc, p);
  }
  // pipeline: lstm(l,c) at launch n = c + 2l; gemm(l,c) at n = c + 2l - 1
  for (int n = 0; n <= 21; ++n) {
    Plan p = {};
    for (int l = 0; l < 4; ++l) {
      const int c = n - 2 * l;
      if (c >= 0 && c < NC_) { p.ll[p.nl] = l; p.lc[p.nl] = c; p.nl++; }
    }
    for (int l = 0; l < 4; ++l) {
      const int c = n + 1 - 2 * l;
      if (c >= 0 && c < NC_) { p.gl[p.ng] = l; p.gc[p.ng] = c; p.ng++; }
    }
    const int grid = p.nl * 32 + p.ng * 64;
    fused_kernel<<<grid, 768, 0, stream>>>(x, flag, wfu, xg, hrp, h3, sth, stc, p);
  }

  linear_kernel<<<B_ * OUT_ * 2, 256, 0, stream>>>(h3, wf + LINWF_O, wf + LINBF_O, lin);
  mel_kernel<<<B_ * OUT_ * 2, 256, 0, stream>>>(lin, m1, melw, melb, 0, flag);
  mel_kernel<<<B_ * OUT_ * 2, 256, 0, stream>>>(m1, m2, melw, melb, 1, flag);
  mel_kernel<<<B_ * OUT_ * 2, 256, 0, stream>>>(m2, m1, melw, melb, 2, flag);
  res_kernel<<<R_ / 4, 256, 0, stream>>>(lin, m1, resw, resb, d_out, flag);
}

// Round 12
// 1510.649 us; speedup vs baseline: 13.1472x; 1.3301x over previous
//
#include <hip/hip_runtime.h>
#include <hip/hip_bf16.h>

#define B_ 32
#define S_ 512
#define IN_ 300
#define H_ 180
#define G4_ 720
#define OUT_ 60
#define R_ 16384
#define TC_ 32
#define NC_ 16
#define NPK_ 92

// packed-weight region word offsets (wfu = uint/float view of same region)
#define PWHH_O  0u        // uints [4][92][720] f16-pair Whh^T = 264,960
#define PW0_O   264960u   // uints [720][150] f16-pair Wih0 = 108,000
#define PWR_O   372960u   // uints [3][720][90] f16-pair WihR = 194,400
#define BIASF_O 567360u   // fp32 [4][720] (bih+bhh) = 2,880
#define LINWF_O 570240u   // fp32 [60][180] = 10,800
#define LINBF_O 581040u   // fp32 [60]
#define WFT_    581100u

// ws float offsets (total 9,105,901 fl = 36.4 MB; ws >= 40 MB measured)
#define XG_O   0u         // [4 layers][2 ring][1024][720] fp32 = 5,898,240
#define HR_O   5898240u   // [3 layers][2 ring][1024][180] fp32 = 1,105,920
#define H3_O   7004160u   // bf16 [16384][180] = 1,474,560 fl
#define WFU_O  8478720u   // 581,100 fl
#define STH_O  9059820u   // [4][32][180]
#define STC_O  9082860u
#define FLAG_O 9105900u
#define XGSLOT 737280
#define HRSLOT 184320

#if defined(__has_builtin)
#if __has_builtin(__builtin_amdgcn_fdot2)
#define HAVE_FDOT2 1
#endif
#endif

typedef _Float16 f16x2 __attribute__((ext_vector_type(2)));

struct Plan {
  int nl; int ll[4]; int lc[4];
  int ng; int gl[4]; int gc[4];
};

__device__ __forceinline__ float sigf(float x)   { return 1.f / (1.f + __expf(-x)); }
__device__ __forceinline__ float tanhf2(float x) { return 2.f / (1.f + __expf(-2.f * x)) - 1.f; }
__device__ __forceinline__ float toF(__hip_bfloat16 x) { return __bfloat162float(x); }
__device__ __forceinline__ float ldr(const void* p, long i, int fl) {
  return fl ? ((const float*)p)[i] : toF(((const __hip_bfloat16*)p)[i]);
}
__device__ __forceinline__ unsigned f16b(_Float16 h) {
  union { _Float16 f; unsigned short s; } x; x.f = h; return x.s;
}
__device__ __forceinline__ float h2f(unsigned s) {
  union { unsigned short s; _Float16 f; } x; x.s = (unsigned short)(s & 0xFFFFu);
  return (float)x.f;
}
__device__ __forceinline__ f16x2 u2h(unsigned u) {
  union { unsigned u; f16x2 v; } x; x.u = u; return x.v;
}
__device__ __forceinline__ float fd2(unsigned hu, unsigned wu, float acc) {
#ifdef HAVE_FDOT2
  return __builtin_amdgcn_fdot2(u2h(hu), u2h(wu), acc, false);
#else
  return acc + h2f(hu) * h2f(wu) + h2f(hu >> 16) * h2f(wu >> 16);
#endif
}
__device__ __forceinline__ unsigned packpair_f32(float lo, float hi) {
  return f16b((_Float16)lo) | (f16b((_Float16)hi) << 16);
}
__device__ __forceinline__ unsigned packpair_bf16(unsigned u) {
  union { unsigned v; float f; } a, b;
  a.v = u << 16; b.v = u & 0xFFFF0000u;
  return packpair_f32(a.f, b.f);
}

// 23 groups x 4 Whh pair-words = 92 named scalars (SROA-proof, asm-pinned)
#define REP23(M) M(0) M(1) M(2) M(3) M(4) M(5) M(6) M(7) M(8) M(9) M(10) \
  M(11) M(12) M(13) M(14) M(15) M(16) M(17) M(18) M(19) M(20) M(21) M(22)
#define LW(n) \
  unsigned w##n##a = wp0[(4*n+0)*G4_], w##n##b = wp0[(4*n+1)*G4_], \
           w##n##c = wp0[(4*n+2)*G4_], w##n##d = wp0[(4*n+3)*G4_];
#define PW(n) \
  asm volatile("" : "+v"(w##n##a), "+v"(w##n##b), "+v"(w##n##c), "+v"(w##n##d));
#define ST(n) { \
  const uint4 hh = *(const uint4*)&hpk[4*n]; \
  a0 = fd2(hh.x, w##n##a, a0); a1 = fd2(hh.y, w##n##b, a1); \
  a2 = fd2(hh.z, w##n##c, a2); a3 = fd2(hh.w, w##n##d, a3); }

// ---------------------------------------------------------------------------
__global__ __launch_bounds__(256) void detect_kernel(
    const unsigned short* __restrict__ xw, int* __restrict__ flag) {
  __shared__ int cnt;
  if (threadIdx.x == 0) cnt = 0;
  __syncthreads();
  int lc = 0;
  for (int i = threadIdx.x; i < 2048; i += 256) {
    const int e = (xw[i] >> 7) & 0xFF;
    if (e >= 0xC0 || (e > 0 && e < 0x40)) lc++;
  }
  atomicAdd(&cnt, lc);
  __syncthreads();
  if (threadIdx.x == 0) *flag = (cnt > 100) ? 1 : 0;
}

// ---------------------------------------------------------------------------
// prep: Whh packed [l][jp][o]; Wih0 packed [o][150]; WihR packed [l][o][90];
// bias/linw/linb fp32.
// ---------------------------------------------------------------------------
__global__ __launch_bounds__(256) void prep_kernel(
    const void* __restrict__ wih0, const void* __restrict__ wihr,
    const void* __restrict__ whh,  const void* __restrict__ bih,
    const void* __restrict__ bhh,  const void* __restrict__ linw,
    const void* __restrict__ linb, float* __restrict__ wf,
    const int* __restrict__ flag) {
  const unsigned i = blockIdx.x * 256u + threadIdx.x;
  if (i >= WFT_) return;
  const int fl = *flag;
  if (i < PW0_O) {            // Whh packed transposed
    const unsigned l = i / 66240u, r = i % 66240u;
    const unsigned jp = r / 720u, o = r % 720u;
    unsigned u = 0u;
    if (jp < 90u) {
      const long b = (long)l * 129600 + (long)o * H_;
      u = packpair_f32(ldr(whh, b + 2 * jp, fl), ldr(whh, b + 2 * jp + 1, fl));
    }
    ((unsigned*)wf)[i] = u;
    return;
  }
  if (i < PWR_O) {            // Wih0 [o][150] pairs
    const unsigned j = i - PW0_O, o = j / 150u, kp = j % 150u;
    const long b = (long)o * IN_;
    ((unsigned*)wf)[i] =
        packpair_f32(ldr(wih0, b + 2 * kp, fl), ldr(wih0, b + 2 * kp + 1, fl));
    return;
  }
  if (i < BIASF_O) {          // WihR [l][o][90] pairs
    const unsigned j = i - PWR_O, l = j / 64800u, r = j % 64800u;
    const unsigned o = r / 90u, kp = r % 90u;
    const long b = (long)l * 129600 + (long)o * H_;
    ((unsigned*)wf)[i] =
        packpair_f32(ldr(wihr, b + 2 * kp, fl), ldr(wihr, b + 2 * kp + 1, fl));
    return;
  }
  float v;
  if (i < LINWF_O)      { const unsigned j = i - BIASF_O; v = ldr(bih, j, fl) + ldr(bhh, j, fl); }
  else if (i < LINBF_O) v = ldr(linw, i - LINWF_O, fl);
  else                  v = ldr(linb, i - LINBF_O, fl);
  wf[i] = v;
}

// ---------------------------------------------------------------------------
// fused: blocks [0, nl*32) = LSTM jobs; rest = barrier GEMM, f16-pair dot2,
// 3x 64x64 tiles per 768-block (proven tiling/barrier skeleton, halved VALU
// and LDS traffic vs fp32).
// ---------------------------------------------------------------------------
__global__ __launch_bounds__(768, 3) void fused_kernel(
    const void* __restrict__ x, const int* __restrict__ flag,
    const unsigned* __restrict__ wfu,
    float* __restrict__ xg, float* __restrict__ hr,
    __hip_bfloat16* __restrict__ h3,
    float* __restrict__ sth, float* __restrict__ stc, Plan p) {
  __shared__ __align__(16) unsigned hpk[NPK_];
  __shared__ float gbuf[G4_];
  __shared__ __align__(16) unsigned Asu[3][10][68];
  __shared__ __align__(16) unsigned Bsu[3][10][68];

  const int bid = blockIdx.x;
  if (bid < p.nl * 32) {
    // ---------------- LSTM (unchanged proven body) ----------------
    const int j = bid >> 5, b = bid & 31;
    const int l = p.ll[j], c = p.lc[j];
    const int o = threadIdx.x;
    const bool act = o < G4_;
    const int oc = act ? o : 0;
    const unsigned* wp0 = wfu + PWHH_O + (unsigned)l * (NPK_ * G4_) + oc;
    REP23(LW)
    REP23(PW)
    const float* xgs = xg + (long)(l * 2 + (c & 1)) * XGSLOT;
    float* hrs = hr + (long)((l < 3 ? l : 0) * 2 + (c & 1)) * HRSLOT;
    float cst = 0.f;
    if (o == 180 || o == 181) hpk[o - 90] = 0u;
    if (o < H_) {
      float h = 0.f;
      if (c != 0) { h = sth[(l * 32 + b) * H_ + o]; cst = stc[(l * 32 + b) * H_ + o]; }
      const unsigned v = f16b((_Float16)h);
      const unsigned nx = __shfl_down(v, 1);
      if ((o & 1) == 0) hpk[o >> 1] = v | (nx << 16);
    }
    const float* xgp = xgs + (long)b * TC_ * G4_ + oc;
    float xcur = xgp[0];
    __syncthreads();
    for (int tl = 0; tl < TC_; ++tl) {
      {
        float a0 = xcur, a1 = 0.f, a2 = 0.f, a3 = 0.f;
        REP23(ST)
        const float acc = (a0 + a1) + (a2 + a3);
        const bool isg = (o >= 2 * H_) && (o < 3 * H_);
        if (act) gbuf[o] = isg ? tanhf2(acc) : sigf(acc);
        const int tn = (tl + 1 < TC_) ? tl + 1 : tl;
        xcur = xgp[(long)tn * G4_];
      }
      __syncthreads();
      if (o < H_) {
        cst = gbuf[H_ + o] * cst + gbuf[o] * gbuf[2 * H_ + o];
        const float h = gbuf[3 * H_ + o] * tanhf2(cst);
        if (l < 3) hrs[(b * TC_ + tl) * H_ + o] = h;
        else h3[((long)b * S_ + c * TC_ + tl) * H_ + o] = __float2bfloat16(h);
        const unsigned v = f16b((_Float16)h);
        const unsigned nx = __shfl_down(v, 1);
        if ((o & 1) == 0) hpk[o >> 1] = v | (nx << 16);
        if (tl == TC_ - 1) {
          sth[(l * 32 + b) * H_ + o] = h; stc[(l * 32 + b) * H_ + o] = cst;
        }
      }
      __syncthreads();
    }
    return;
  }

  // ---------------- GEMM: f16-pair dot2, proven barrier tiling ----------
  const int gb = bid - p.nl * 32;
  const int g = threadIdx.x >> 8, t = threadIdx.x & 255;
  const int ti = gb * 3 + g;              // grid sized exactly: ti < ng*192
  const int jj = ti / 192, idx = ti % 192;
  const int rt = idx & 15, ct = idx >> 4;
  const int l = p.gl[jj], c = p.gc[jj];
  const int fl = *flag;
  const int KP = (l == 0) ? 150 : 90;     // k-pairs
  const unsigned* Wp = (l == 0) ? (wfu + PW0_O)
                                : (wfu + PWR_O + (unsigned)(l - 1) * 64800u);
  const float* bias = (const float*)wfu + BIASF_O + (unsigned)l * G4_;
  const float* hA = (l == 0) ? nullptr
                  : hr + (long)((l - 1) * 2 + (c & 1)) * HRSLOT;
  float* dst = xg + (long)(l * 2 + (c & 1)) * XGSLOT;
  const int rho0 = rt * 64, o0 = ct * 64;
  const int tx = t & 15, ty = t >> 4;
  float acc[4][4] = {};
  for (int kp0 = 0; kp0 < KP; kp0 += 10) {
    for (int e = t; e < 640; e += 256) {
      const int rl = e / 10, pp = e % 10;
      const int rho = rho0 + rl;
      unsigned av;
      if (l == 0) {
        const int bb = rho >> 5, tl = rho & 31;
        const long gr = (long)bb * S_ + c * TC_ + tl;
        if (fl == 0) av = packpair_bf16(((const unsigned*)x)[gr * 150 + kp0 + pp]);
        else { const float2 f = ((const float2*)x)[gr * 150 + kp0 + pp];
               av = packpair_f32(f.x, f.y); }
      } else {
        const float2 f = ((const float2*)hA)[(long)rho * 90 + kp0 + pp];
        av = packpair_f32(f.x, f.y);
      }
      Asu[g][pp][rl] = av;
      const int o = o0 + rl;
      Bsu[g][pp][rl] = (o < G4_) ? Wp[(long)o * KP + kp0 + pp] : 0u;
    }
    __syncthreads();
#pragma unroll
    for (int pp = 0; pp < 10; ++pp) {
      const uint4 a4 = *(const uint4*)&Asu[g][pp][ty * 4];
      const uint4 b4 = *(const uint4*)&Bsu[g][pp][tx * 4];
      const unsigned av[4] = {a4.x, a4.y, a4.z, a4.w};
      const unsigned bv[4] = {b4.x, b4.y, b4.z, b4.w};
#pragma unroll
      for (int i = 0; i < 4; ++i)
#pragma unroll
        for (int j2 = 0; j2 < 4; ++j2) acc[i][j2] = fd2(av[i], bv[j2], acc[i][j2]);
    }
    __syncthreads();
  }
#pragma unroll
  for (int i = 0; i < 4; ++i) {
    const int rho = rho0 + ty * 4 + i;
#pragma unroll
    for (int j2 = 0; j2 < 4; ++j2) {
      const int o = o0 + tx * 4 + j2;
      if (o < G4_) dst[(long)rho * G4_ + o] = acc[i][j2] + bias[o];
    }
  }
}

// ---------------------------------------------------------------------------
// linear as tiled GEMM: [16384 x 180] @ [180 x 60] -> out[b][c][s].
// 256 blocks x 256 threads, one 64x64 tile each (proven skeleton, coalesced).
// ---------------------------------------------------------------------------
__global__ __launch_bounds__(256) void linear_kernel(
    const __hip_bfloat16* __restrict__ h, const float* __restrict__ linw,
    const float* __restrict__ linb, float* __restrict__ out) {
  __shared__ __align__(16) float Ast[20][68];
  __shared__ __align__(16) float Bst[20][68];
  const int bt = blockIdx.x;
  const int b = bt >> 3, st0 = (bt & 7) * 64;
  const int t = threadIdx.x, tx = t & 15, ty = t >> 4;
  float acc[4][4] = {};
  for (int k0 = 0; k0 < H_; k0 += 20) {
    for (int e = t; e < 1280; e += 256) {
      const int rl = e / 20, kk = e % 20;
      Ast[kk][rl] = toF(h[(long)(b * S_ + st0 + rl) * H_ + k0 + kk]);
      Bst[kk][rl] = (rl < OUT_) ? linw[rl * H_ + k0 + kk] : 0.f;
    }
    __syncthreads();
#pragma unroll
    for (int kk = 0; kk < 20; ++kk) {
      const float4 a4 = *(const float4*)&Ast[kk][ty * 4];
      const float4 b4 = *(const float4*)&Bst[kk][tx * 4];
      const float av[4] = {a4.x, a4.y, a4.z, a4.w};
      const float bv[4] = {b4.x, b4.y, b4.z, b4.w};
#pragma unroll
      for (int i = 0; i < 4; ++i)
#pragma unroll
        for (int j2 = 0; j2 < 4; ++j2) acc[i][j2] += av[i] * bv[j2];
    }
    __syncthreads();
  }
#pragma unroll
  for (int i = 0; i < 4; ++i) {
    const int s = st0 + ty * 4 + i;
#pragma unroll
    for (int j2 = 0; j2 < 4; ++j2) {
      const int c = tx * 4 + j2;
      if (c < OUT_) out[((long)b * OUT_ + c) * S_ + s] = acc[i][j2] + linb[c];
    }
  }
}

// ---------------------------------------------------------------------------
__global__ __launch_bounds__(256) void mel_kernel(
    const float* __restrict__ in, float* __restrict__ out,
    const void* __restrict__ mw, const void* __restrict__ mb,
    int l, const int* __restrict__ flag) {
  const int fl = *flag;
  const int idx = blockIdx.x;
  const int s = (idx & 1) * 256 + threadIdx.x;
  const int c = (idx >> 1) % OUT_;
  const int b = idx / (2 * OUT_);
  const int j = c % 3, i = c / 3;
  float acc = ldr(mb, (l * 3 + j) * 20 + i, fl);
  const long wbase = (long)((l * 3 + j) * 20 + i) * 15;
#pragma unroll
  for (int q = 0; q < 3; ++q) {
    const int ch = 3 * i + q + j - 1;
    if (ch < 0 || ch >= OUT_) continue;
    const float* xr = in + ((long)b * OUT_ + ch) * S_;
#pragma unroll
    for (int k = 0; k < 5; ++k) {
      const int sp = s + k - 2;
      if (sp < 0 || sp >= S_) continue;
      acc += ldr(mw, wbase + q * 5 + k, fl) * xr[sp];
    }
  }
  out[((long)b * OUT_ + c) * S_ + s] = acc + in[((long)b * OUT_ + c) * S_ + s];
}

// ---------------------------------------------------------------------------
__global__ __launch_bounds__(256) void res_kernel(
    const float* __restrict__ lin, const float* __restrict__ mel,
    const void* __restrict__ rw, const void* __restrict__ rb,
    void* __restrict__ outp, const int* __restrict__ flag) {
  const int fl = *flag;
  const int q = threadIdx.x >> 6, lane = threadIdx.x & 63;
  const int bs = blockIdx.x * 4 + q;
  const int b = bs / S_, s = bs % S_;
  if (lane >= OUT_) return;
  const int c = lane;
  float acc = ldr(rb, c, fl);
  const float* x0 = lin + ((long)b * OUT_ + c) * S_;
  const float* x1 = mel + ((long)b * OUT_ + c) * S_;
#pragma unroll
  for (int k = 0; k < 5; ++k) {
    const int sp = s + k - 2;
    if (sp < 0 || sp >= S_) continue;
    acc += ldr(rw, c * 10 + k, fl) * x0[sp] + ldr(rw, c * 10 + 5 + k, fl) * x1[sp];
  }
  const long oi = (long)bs * OUT_ + c;
  if (fl == 0) ((__hip_bfloat16*)outp)[oi] = __float2bfloat16(acc);
  else ((float*)outp)[oi] = acc;
}

// ---------------------------------------------------------------------------
extern "C" void kernel_launch(void* const* d_in, const int* in_sizes, int n_in,
                              void* d_out, int out_size, void* d_ws, size_t ws_size,
                              hipStream_t stream) {
  const void* x    = d_in[0];
  const void* wih0 = d_in[1];
  const void* wihr = d_in[2];
  const void* whh  = d_in[3];
  const void* bih  = d_in[4];
  const void* bhh  = d_in[5];
  const void* linw = d_in[6];
  const void* linb = d_in[7];
  const void* melw = d_in[8];
  const void* melb = d_in[9];
  const void* resw = d_in[10];
  const void* resb = d_in[11];

  float* ws = (float*)d_ws;
  float* xg = ws + XG_O;
  float* hrp = ws + HR_O;
  __hip_bfloat16* h3 = (__hip_bfloat16*)(ws + H3_O);
  float* wf = ws + WFU_O;
  const unsigned* wfu = (const unsigned*)wf;
  float* sth = ws + STH_O;
  float* stc = ws + STC_O;
  int* flag = (int*)(ws + FLAG_O);
  float* lin = ws + XG_O;            // epilogue aliases dead xg region
  float* m1 = lin + 983040;
  float* m2 = m1 + 983040;

  detect_kernel<<<1, 256, 0, stream>>>((const unsigned short*)x, flag);
  prep_kernel<<<(WFT_ + 255) / 256, 256, 0, stream>>>(
      wih0, wihr, whh, bih, bhh, linw, linb, wf, flag);

  // prologue: gemm(0,0) only
  {
    Plan p = {};
    p.nl = 0; p.ng = 1; p.gl[0] = 0; p.gc[0] = 0;
    fused_kernel<<<64, 768, 0, stream>>>(x, flag, wfu, xg, hrp, h3, sth, stc, p);
  }
  // pipeline: lstm(l,c) at launch n = c + 2l; gemm(l,c) at n = c + 2l - 1
  for (int n = 0; n <= 21; ++n) {
    Plan p = {};
    for (int l = 0; l < 4; ++l) {
      const int c = n - 2 * l;
      if (c >= 0 && c < NC_) { p.ll[p.nl] = l; p.lc[p.nl] = c; p.nl++; }
    }
    for (int l = 0; l < 4; ++l) {
      const int c = n + 1 - 2 * l;
      if (c >= 0 && c < NC_) { p.gl[p.ng] = l; p.gc[p.ng] = c; p.ng++; }
    }
    const int grid = p.nl * 32 + p.ng * 64;
    fused_kernel<<<grid, 768, 0, stream>>>(x, flag, wfu, xg, hrp, h3, sth, stc, p);
  }

  linear_kernel<<<256, 256, 0, stream>>>(h3, wf + LINWF_O, wf + LINBF_O, lin);
  mel_kernel<<<B_ * OUT_ * 2, 256, 0, stream>>>(lin, m1, melw, melb, 0, flag);
  mel_kernel<<<B_ * OUT_ * 2, 256, 0, stream>>>(m1, m2, melw, melb, 1, flag);
  mel_kernel<<<B_ * OUT_ * 2, 256, 0, stream>>>(m2, m1, melw, melb, 2, flag);
  res_kernel<<<R_ / 4, 256, 0, stream>>>(lin, m1, resw, resb, d_out, flag);
}